// Round 8
// baseline (249.690 us; speedup 1.0000x reference)
//
#include <hip/hip_runtime.h>
#include <math.h>
#include <utility>

// B=16, T=16, FDIM=64, ODIM=8, NQ=10, NA=4, LAYERS=2, DEGREE=3.
// ROUND 8: 2 blocks per b (grid 32), 8 waves per block (512 thr), wave owns
// column (b, a = sub*8 + w): 1024 complex amps in regs (n = lane*16 + r).
// 2 waves/SIMD (launch_bounds(512,2) -> VGPR cap 256; we use ~136): the
// second wave's issue hides the first's DS/DPP/trans stalls (round 7 was
// 1 wave/SIMD, ~70% stalled at 108us; round 6 showed 4 waves/SIMD spills).
// Gates on bit<4: thread-local. bit>=4: xor1/2/8 DPP, xor16/32 permlane
// swap (VALU), xor4 shfl. Rank-1 pcphase mixes (round-5 algebra):
//   M_k = conj(e_k) I + (e_k - conj(e_k)) u0 u0^dag,  u0 = (prepare)|0>.
// Mix = LDS pre-reduction of the 8 in-block partials (4-slot tree) -> ONE
// 8KB block partial to global -> 16-wave group barrier (proven cnt/gen
// monotonic pattern) -> read own (LDS) + 1 remote partial. Mend mix deleted
// (unitary on ancilla; expvals trace it out).

struct Gate { int ry; int tbit; int cbit; int pidx; };
struct GateTab { Gate g[40]; };

constexpr GateTab make_gates1() {
  GateTab tb{};
  int pos = 0, idx = 0;
  for (int i = 0; i < 10; ++i) { tb.g[pos] = Gate{1, 9 - i, -1, idx}; ++pos; ++idx; }
  for (int i = 9; i >= 0; --i) { tb.g[pos] = Gate{0, 9 - ((i + 1) % 10), 9 - i, idx}; ++pos; ++idx; }
  for (int i = 0; i < 10; ++i) { tb.g[pos] = Gate{1, 9 - i, -1, idx}; ++pos; ++idx; }
  for (int k = 0; k < 10; ++k) {
    int i = (k == 0) ? 9 : (k - 1);
    tb.g[pos] = Gate{0, 9 - ((i + 9) % 10), 9 - i, idx}; ++pos; ++idx;
  }
  return tb;
}
constexpr GateTab GTC = make_gates1();

__device__ __forceinline__ int insert_zero(int v, int p) {
  return ((v >> p) << (p + 1)) | (v & ((1 << p) - 1));
}
__device__ __forceinline__ float2 cmul(float2 A, float2 B) {
  return make_float2(A.x * B.x - A.y * B.y, A.x * B.y + A.y * B.x);
}
__device__ __forceinline__ float2 conj2(float2 A) { return make_float2(A.x, -A.y); }

// ---------------- cross-lane xor (DPP / permlane / shfl) ----------------
template<int XM>
__device__ __forceinline__ float lxor(float v) {
  if constexpr (XM == 1) {
    int r = __builtin_amdgcn_update_dpp(__float_as_int(v), __float_as_int(v),
                                        0xB1, 0xF, 0xF, true);
    return __int_as_float(r);
  } else if constexpr (XM == 2) {
    int r = __builtin_amdgcn_update_dpp(__float_as_int(v), __float_as_int(v),
                                        0x4E, 0xF, 0xF, true);
    return __int_as_float(r);
  } else if constexpr (XM == 8) {
    int r = __builtin_amdgcn_update_dpp(__float_as_int(v), __float_as_int(v),
                                        0x128, 0xF, 0xF, true);
    return __int_as_float(r);
  } else if constexpr (XM == 16) {
#if __has_builtin(__builtin_amdgcn_permlane16_swap)
    unsigned uv = __float_as_uint(v);
    auto r = __builtin_amdgcn_permlane16_swap(uv, uv, false, false);
    return __uint_as_float(r[0] ^ r[1] ^ uv);
#else
    return __shfl_xor(v, 16, 64);
#endif
  } else if constexpr (XM == 32) {
#if __has_builtin(__builtin_amdgcn_permlane32_swap)
    unsigned uv = __float_as_uint(v);
    auto r = __builtin_amdgcn_permlane32_swap(uv, uv, false, false);
    return __uint_as_float(r[0] ^ r[1] ^ uv);
#else
    return __shfl_xor(v, 32, 64);
#endif
  } else {
    return __shfl_xor(v, XM, 64);
  }
}

__device__ __forceinline__ float wave_sum(float v) {
  v += lxor<1>(v);
  v += lxor<2>(v);
  v += lxor<4>(v);
  v += lxor<8>(v);
  v += lxor<16>(v);
  v += lxor<32>(v);
  return v;
}

// ---------------- per-b group barrier (16 wave-parties) ----------------
// Monotonic words, zero-init at module load, never reset (rounds 3-7 proven).
struct alignas(128) GBar {
  unsigned cnt;        // barrier wave-arrivals, monotonic
  unsigned gen;        // completed rounds, monotonic
  unsigned done;       // block completions, monotonic
  unsigned pad[29];
};
__device__ GBar g_gb[16];

__device__ __forceinline__ void group_barrier16(int b, int lane) {
  unsigned snap = __hip_atomic_load(&g_gb[b].gen, __ATOMIC_RELAXED, __HIP_MEMORY_SCOPE_AGENT);
  if (lane == 0) {
    unsigned old = __hip_atomic_fetch_add(&g_gb[b].cnt, 1u, __ATOMIC_ACQ_REL,
                                          __HIP_MEMORY_SCOPE_AGENT);
    if ((old & 15u) == 15u)
      __hip_atomic_store(&g_gb[b].gen, snap + 1u, __ATOMIC_RELEASE,
                         __HIP_MEMORY_SCOPE_AGENT);
  }
  while (__hip_atomic_load(&g_gb[b].gen, __ATOMIC_RELAXED, __HIP_MEMORY_SCOPE_AGENT) == snap)
    __builtin_amdgcn_s_sleep(1);
  (void)__hip_atomic_load(&g_gb[b].gen, __ATOMIC_ACQUIRE, __HIP_MEMORY_SCOPE_AGENT);
}

// ---------------- register/shuffle gate engine ----------------
template<int P>
__device__ __forceinline__ void ry_gate(float2 (&a)[16], float c, float s, int lane) {
  if constexpr (P < 4) {
    constexpr int m = 1 << P;
#pragma unroll
    for (int r0 = 0; r0 < 16; ++r0) {
      if (!(r0 & m)) {
        int r1 = r0 | m;
        float2 a0 = a[r0], a1 = a[r1];
        a[r0] = make_float2(c * a0.x - s * a1.x, c * a0.y - s * a1.y);
        a[r1] = make_float2(s * a0.x + c * a1.x, s * a0.y + c * a1.y);
      }
    }
  } else {
    constexpr int xm = 1 << (P - 4);
    bool up = (lane >> (P - 4)) & 1;
    float sg = up ? s : -s;
#pragma unroll
    for (int r = 0; r < 16; ++r) {
      float wx = lxor<xm>(a[r].x);
      float wy = lxor<xm>(a[r].y);
      a[r].x = c * a[r].x + sg * wx;
      a[r].y = c * a[r].y + sg * wy;
    }
  }
}

template<int P, int Q>
__device__ __forceinline__ void crx_gate(float2 (&a)[16], float c, float s, int lane) {
  if constexpr (P < 4) {
    constexpr int m = 1 << P;
#pragma unroll
    for (int r0 = 0; r0 < 16; ++r0) {
      if (!(r0 & m)) {
        int r1 = r0 | m;
        bool act;
        if constexpr (Q < 4) act = (r0 >> Q) & 1;
        else act = (lane >> (Q - 4)) & 1;
        if (act) {
          float2 a0 = a[r0], a1 = a[r1];
          a[r0] = make_float2(c * a0.x + s * a1.y, c * a0.y - s * a1.x);
          a[r1] = make_float2(c * a1.x + s * a0.y, c * a1.y - s * a0.x);
        }
      }
    }
  } else {
    constexpr int xm = 1 << (P - 4);
#pragma unroll
    for (int r = 0; r < 16; ++r) {
      float wx = lxor<xm>(a[r].x);
      float wy = lxor<xm>(a[r].y);
      bool act;
      if constexpr (Q < 4) act = (r >> Q) & 1;
      else act = (lane >> (Q - 4)) & 1;
      if (act) {
        float nx = c * a[r].x + s * wy;
        float ny = c * a[r].y - s * wx;
        a[r].x = nx; a[r].y = ny;
      }
    }
  }
}

template<bool ADJ, int G>
__device__ __forceinline__ void one_gate(float2 (&a)[16], const float2 (&sc)[40], int lane) {
  constexpr Gate g = GTC.g[ADJ ? (39 - G) : G];
  float2 scv = sc[g.pidx];            // constexpr index -> VGPR
  float s = ADJ ? -scv.x : scv.x;
  float c = scv.y;
  if constexpr (g.ry != 0) ry_gate<g.tbit>(a, c, s, lane);
  else crx_gate<g.tbit, g.cbit>(a, c, s, lane);
}

template<bool ADJ, int... I>
__device__ __forceinline__ void run_layer_impl(float2 (&a)[16], const float2 (&sc)[40],
                                               int lane, std::integer_sequence<int, I...>) {
  (one_gate<ADJ, I>(a, sc, lane), ...);
}

// Preload the 40-entry (sin,cos) table into registers, then run the 40 gates.
template<bool ADJ>
__device__ __forceinline__ void run_layer(float2 (&a)[16], const float2* sc, int lane) {
  float2 rsc[40];
#pragma unroll
  for (int i = 0; i < 40; ++i) rsc[i] = sc[i];
  run_layer_impl<ADJ>(a, rsc, lane, std::make_integer_sequence<int, 40>{});
}

// ---------------- the fused kernel ----------------
__global__ __launch_bounds__(512, 2) void k_fused(const float* __restrict__ x,
                                                  const float* __restrict__ W_fp,
                                                  const float* __restrict__ b_fp,
                                                  const float* __restrict__ prep,
                                                  const float* __restrict__ sig,
                                                  const float* __restrict__ qff,
                                                  const float* __restrict__ W_out,
                                                  const float* __restrict__ b_out,
                                                  float* __restrict__ out,
                                                  float4* __restrict__ part1,
                                                  float4* __restrict__ part2,
                                                  float* __restrict__ sv) {
  int blk = blockIdx.x;
  int b = blk >> 1, sub = blk & 1;
  int tid = threadIdx.x;
  int w = tid >> 6, lane = tid & 63;
  int aa = sub * 8 + w;               // this wave's ancilla column

  __shared__ __align__(16) float h[8][64];   // per-wave feature row (t = aa)
  __shared__ float2 scs[8][80];              // per-wave ts (sin,cos)
  __shared__ float2 qscs[40];
  __shared__ float2 ps[32];                  // prep (sin,cos of th/2)
  __shared__ float2 es[4];                   // e^{i sig_k} = (cos, sin)
  __shared__ float2 u0s[16];                 // u0 = (prepare)|0>_anc
  __shared__ float4 R[4][512];               // 32 KB 4-slot reduction buffer

  // sv zero (ordered before the other block's atomics via barrier chain)
  if (sub == 0 && w == 0 && lane < 30) sv[b * 30 + lane] = 0.f;

  // ---- phase 0a: h row for (b, t=aa); stage small tables ----
  {
    int f = lane, k = f >> 1;
    float div = expf(-(float)(2 * k) * (logf(10000.f) / 64.f));
    float ang = (float)aa * div;
    float pe = (f & 1) ? cosf(ang) : sinf(ang);
    h[w][f] = x[(b * 64 + f) * 16 + aa] + pe;
  }
  if (w == 0) {
    if (lane < 32) {
      float s, c;
      sincosf(0.5f * prep[lane], &s, &c);
      ps[lane] = make_float2(s, c);
    } else if (lane < 36) {
      float s, c;
      sincosf(sig[lane - 32], &s, &c);
      es[lane - 32] = make_float2(c, s);
    }
  } else if (w == 1 && lane < 40) {
    float s, c;
    sincosf(0.5f * qff[lane], &s, &c);
    qscs[lane] = make_float2(s, c);
  }
  __syncthreads();

  // ---- phase 0b: wave 0 builds u0 (16 complex, register evolution) ----
  if (w == 0) {
    float2 v[16];
#pragma unroll
    for (int i = 0; i < 16; ++i) v[i] = make_float2(i == 0 ? 1.f : 0.f, 0.f);
    for (int ly = 0; ly < 4; ++ly) {
#pragma unroll
      for (int qi = 0; qi < 4; ++qi) {
        int p = 3 - qi;
        float2 rc = ps[ly * 8 + qi * 2 + 0];      // ry
        {
          float s = rc.x, c = rc.y;
#pragma unroll
          for (int m = 0; m < 8; ++m) {
            int a0 = insert_zero(m, p), a1 = a0 | (1 << p);
            float2 t0 = v[a0], t1 = v[a1];
            v[a0] = make_float2(c * t0.x - s * t1.x, c * t0.y - s * t1.y);
            v[a1] = make_float2(s * t0.x + c * t1.x, s * t0.y + c * t1.y);
          }
        }
        rc = ps[ly * 8 + qi * 2 + 1];             // rz
        {
          float s = rc.x, c = rc.y;
#pragma unroll
          for (int m = 0; m < 8; ++m) {
            int a0 = insert_zero(m, p), a1 = a0 | (1 << p);
            float2 t0 = v[a0], t1 = v[a1];
            v[a0] = make_float2(c * t0.x + s * t0.y, c * t0.y - s * t0.x);
            v[a1] = make_float2(c * t1.x - s * t1.y, c * t1.y + s * t1.x);
          }
        }
      }
#pragma unroll
      for (int i = 0; i < 3; ++i) {
        int pc = 3 - i, pt = 2 - i;
#pragma unroll
        for (int m = 0; m < 4; ++m) {
          int mm = insert_zero(m, pt);
          mm = insert_zero(mm, pc);
          int a0 = mm | (1 << pc), a1 = a0 | (1 << pt);
          float2 t0 = v[a0], t1 = v[a1];
          v[a0] = t1; v[a1] = t0;
        }
      }
    }
    if (lane == 0) {
#pragma unroll
      for (int i = 0; i < 16; ++i) u0s[i] = v[i];
    }
  }

  // ---- phase 0c: ts dot products for this wave's column (t = aa) ----
  {
    const float4* h4 = (const float4*)&h[w][0];
    for (int j = lane; j < 80; j += 64) {
      float acc = b_fp[j];
      const float4* w4 = (const float4*)(W_fp + j * 64);
#pragma unroll
      for (int k4 = 0; k4 < 16; ++k4) {
        float4 hh = h4[k4], ww = w4[k4];
        acc += hh.x * ww.x + hh.y * ww.y + hh.z * ww.z + hh.w * ww.w;
      }
      float sg = 1.f / (1.f + expf(-acc));
      float s, c;
      sincosf(sg * 3.14159265358979323846f, &s, &c);   // theta/2 = sigmoid*pi
      scs[w][j] = make_float2(s, c);
    }
  }
  __syncthreads();                     // u0s + scs visible

  float2 u0aa = u0s[aa];
  float2 e0 = es[0], e1 = es[1], e2 = es[2];
  float2 m0  = cmul(u0aa, e0);
  float2 cu0 = conj2(u0aa);
  float2 ceA = conj2(e1);
  float2 wA  = make_float2(-2.f * e1.y * u0aa.y, 2.f * e1.y * u0aa.x);
  float2 ceB = conj2(e2);
  float2 wB  = make_float2(-2.f * e2.y * u0aa.y, 2.f * e2.y * u0aa.x);

  const float2* sc = &scs[w][0];
  float2 a[16];
#pragma unroll
  for (int r = 0; r < 16; ++r) a[r] = make_float2(0.f, 0.f);
  if (lane == 0) a[0] = m0;

  // ---- main loop: k=0 fwd | k=1 mix1+adj | k=2 mix2+fwd | k=3 qff ----
  for (int k = 0; k < 4; ++k) {
    if (k == 1 || k == 2) {
      float2 ce = (k == 1) ? ceA : ceB;
      float2 wk = (k == 1) ? wA : wB;
      float4* part = (k == 1) ? part1 : part2;

      // in-block 8->4->1 reduction of p = cu0 * col into R[0..3]
      __syncthreads();               // R free (prev readers done)
      if (w < 4) {
#pragma unroll
        for (int q = 0; q < 8; ++q) {
          float2 p0 = cmul(cu0, a[2 * q]);
          float2 p1 = cmul(cu0, a[2 * q + 1]);
          R[w][q * 64 + lane] = make_float4(p0.x, p0.y, p1.x, p1.y);
        }
      }
      __syncthreads();
      if (w >= 4) {
#pragma unroll
        for (int q = 0; q < 8; ++q) {
          float4 v = R[w - 4][q * 64 + lane];
          float2 p0 = cmul(cu0, a[2 * q]);
          float2 p1 = cmul(cu0, a[2 * q + 1]);
          R[w - 4][q * 64 + lane] =
              make_float4(v.x + p0.x, v.y + p0.y, v.z + p1.x, v.w + p1.y);
        }
      }
      __syncthreads();
      // block partial (R0+R1+R2+R3) -> global: one float4 per thread
      {
        int idx = w * 64 + lane;     // 0..511
        float4 v0 = R[0][idx], v1 = R[1][idx], v2 = R[2][idx], v3 = R[3][idx];
        part[(size_t)(b * 2 + sub) * 512 + idx] =
            make_float4(v0.x + v1.x + v2.x + v3.x, v0.y + v1.y + v2.y + v3.y,
                        v0.z + v1.z + v2.z + v3.z, v0.w + v1.w + v2.w + v3.w);
      }
      group_barrier16(b, lane);      // release covers stores; acquire for reads

      // s = own block partial (LDS, 4 slots) + 1 remote block partial
      float4 s4[8];
#pragma unroll
      for (int q = 0; q < 8; ++q) {
        float4 v0 = R[0][q * 64 + lane];
        float4 v1 = R[1][q * 64 + lane];
        float4 v2 = R[2][q * 64 + lane];
        float4 v3 = R[3][q * 64 + lane];
        s4[q] = make_float4(v0.x + v1.x + v2.x + v3.x, v0.y + v1.y + v2.y + v3.y,
                            v0.z + v1.z + v2.z + v3.z, v0.w + v1.w + v2.w + v3.w);
      }
      {
        const float4* pp = part + (size_t)(b * 2 + (sub ^ 1)) * 512 + lane;
#pragma unroll
        for (int q = 0; q < 8; ++q) {
          float4 v = pp[q * 64];
          s4[q].x += v.x; s4[q].y += v.y; s4[q].z += v.z; s4[q].w += v.w;
        }
      }
      // col <- ce*col + wk*s
#pragma unroll
      for (int q = 0; q < 8; ++q) {
        float2 a0 = a[2 * q], a1 = a[2 * q + 1];
        a[2 * q] = make_float2(ce.x * a0.x - ce.y * a0.y + wk.x * s4[q].x - wk.y * s4[q].y,
                               ce.x * a0.y + ce.y * a0.x + wk.x * s4[q].y + wk.y * s4[q].x);
        a[2 * q + 1] = make_float2(ce.x * a1.x - ce.y * a1.y + wk.x * s4[q].z - wk.y * s4[q].w,
                                   ce.x * a1.y + ce.y * a1.x + wk.x * s4[q].w + wk.y * s4[q].z);
      }
    }
    // select layers: ONE fwd body (k=0,2 and k=3 qff via nL/scp), ONE adj body
    if (k == 1) {
#pragma unroll 1
      for (int L = 0; L < 2; ++L) run_layer<true>(a, sc + 40 * (1 - L), lane);
    } else {
      const float2* scp = (k == 3) ? &qscs[0] : sc;
      int nL = (k == 3) ? 1 : 2;
#pragma unroll 1
      for (int L = 0; L < nL; ++L) run_layer<false>(a, scp + 40 * L, lane);
    }
  }

  // ---- expvals: per-wave obs -> LDS -> block partial -> global sv atomics ----
  {
    float obs[30];
#pragma unroll
    for (int p = 0; p <= 9; ++p) {
      int i = 9 - p;
      float cr = 0.f, ci = 0.f, zz = 0.f;
      if (p < 4) {
        int m = 1 << p;
#pragma unroll
        for (int r0 = 0; r0 < 16; ++r0) {
          if (!(r0 & m)) {
            float2 A0 = a[r0], A1 = a[r0 | m];
            cr += A0.x * A1.x + A0.y * A1.y;
            ci += A0.x * A1.y - A0.y * A1.x;
            zz += (A0.x * A0.x + A0.y * A0.y) - (A1.x * A1.x + A1.y * A1.y);
          }
        }
      } else {
        int xm = 1 << (p - 4);
        bool up = (lane >> (p - 4)) & 1;
#pragma unroll
        for (int r = 0; r < 16; ++r) {
          float wx = __shfl_xor(a[r].x, xm, 64);
          float wy = __shfl_xor(a[r].y, xm, 64);
          float n2 = a[r].x * a[r].x + a[r].y * a[r].y;
          if (!up) {
            cr += a[r].x * wx + a[r].y * wy;
            ci += a[r].x * wy - a[r].y * wx;
            zz += n2;
          } else {
            zz -= n2;
          }
        }
      }
      obs[i] = 2.f * cr;
      obs[10 + i] = 2.f * ci;
      obs[20 + i] = zz;
    }
#pragma unroll
    for (int j = 0; j < 30; ++j) obs[j] = wave_sum(obs[j]);

    float* Rf = (float*)R;
    __syncthreads();                 // everyone done with R (mix 2 reads)
    if (lane == 0) {
#pragma unroll
      for (int j = 0; j < 30; ++j) Rf[w * 30 + j] = obs[j];
    }
    __syncthreads();
    if (w == 0) {
      if (lane < 30) {
        float v = 0.f;
#pragma unroll
        for (int wv = 0; wv < 8; ++wv) v += Rf[wv * 30 + lane];
        atomicAdd(&sv[b * 30 + lane], v);
      }
      // last-arriving block of the pair computes the output row
      int lastflag = 0;
      if (lane == 0) {
        unsigned old = __hip_atomic_fetch_add(&g_gb[b].done, 1u, __ATOMIC_ACQ_REL,
                                              __HIP_MEMORY_SCOPE_AGENT);
        lastflag = ((old & 1u) == 1u) ? 1 : 0;
      }
      lastflag = __shfl(lastflag, 0, 64);
      if (lastflag) {
        (void)__hip_atomic_load(&g_gb[b].done, __ATOMIC_ACQUIRE, __HIP_MEMORY_SCOPE_AGENT);
        if (lane < 8) {
          float acc = b_out[lane];
#pragma unroll
          for (int j = 0; j < 30; ++j) acc += W_out[lane * 30 + j] * sv[b * 30 + j];
          out[b * 8 + lane] = acc;
        }
      }
    }
  }
}

extern "C" void kernel_launch(void* const* d_in, const int* in_sizes, int n_in,
                              void* d_out, int out_size, void* d_ws, size_t ws_size,
                              hipStream_t stream) {
  const float* x     = (const float*)d_in[0];
  const float* W_fp  = (const float*)d_in[1];
  const float* b_fp  = (const float*)d_in[2];
  const float* prep  = (const float*)d_in[3];
  const float* sig   = (const float*)d_in[4];
  const float* qff   = (const float*)d_in[5];
  const float* W_out = (const float*)d_in[6];
  const float* b_out = (const float*)d_in[7];
  float* out = (float*)d_out;
  (void)in_sizes; (void)n_in; (void)out_size;

  // ws: part1 (256 KB) | part2 (256 KB) | sv (1920 B). Needs ~515 KB.
  char* ws = (char*)d_ws;
  const size_t SZ_PART = (size_t)32 * 512 * 16;   // 32 block-partials * 8 KB
  float4* part1 = (float4*)ws;
  float4* part2 = (float4*)(ws + SZ_PART);
  float*  sv    = (float*)(ws + 2 * SZ_PART);
  (void)ws_size;

  k_fused<<<dim3(32), dim3(512), 0, stream>>>(x, W_fp, b_fp, prep, sig, qff,
                                              W_out, b_out, out, part1, part2, sv);
}

// Round 9
// 163.504 us; speedup vs baseline: 1.5271x; 1.5271x over previous
//
#include <hip/hip_runtime.h>
#include <math.h>
#include <utility>

// B=16, T=16, FDIM=64, ODIM=8, NQ=10, NA=4, LAYERS=2, DEGREE=3.
// ROUND 9 = round 7 geometry (4 blocks/b, grid 64, 4 waves/block, wave owns
// column (b, a=sub*4+w), 1 wave/SIMD, launch_bounds(256,1)) + two changes:
//  1. ONE fwd body + ONE adj body: the phase loop is '#pragma unroll 1' over
//     7 layer-passes with runtime descriptors (round 7/8's k-loop was
//     compiler-unrolled -> ~5 body copies -> >100KB hot code streaming
//     through a 32KB L1I every pass; round 8 proved the stall is a shared
//     per-CU resource: 2 waves/SIMD = exact 2x serialization).
//  2. Packed fp32 gate math: state is float ext_vector_type(2) so ry/crx
//     updates are scalar*vector -> v_pk_mul/v_pk_fma (half the instructions,
//     half the code).
// Rank-1 pcphase mixes (round-5 algebra): M_k = conj(e_k) I +
// (e_k-conj(e_k)) u0 u0^dag, u0=(prepare)|0>. Mend deleted (unitary on
// ancilla). Mix: LDS 4->1 pre-reduction -> ONE 8KB block partial -> 16-wave
// group barrier (monotonic cnt/gen) -> own LDS + 3 remote partials.

typedef float v2f __attribute__((ext_vector_type(2)));

struct Gate { int ry; int tbit; int cbit; int pidx; };
struct GateTab { Gate g[40]; };

constexpr GateTab make_gates1() {
  GateTab tb{};
  int pos = 0, idx = 0;
  for (int i = 0; i < 10; ++i) { tb.g[pos] = Gate{1, 9 - i, -1, idx}; ++pos; ++idx; }
  for (int i = 9; i >= 0; --i) { tb.g[pos] = Gate{0, 9 - ((i + 1) % 10), 9 - i, idx}; ++pos; ++idx; }
  for (int i = 0; i < 10; ++i) { tb.g[pos] = Gate{1, 9 - i, -1, idx}; ++pos; ++idx; }
  for (int k = 0; k < 10; ++k) {
    int i = (k == 0) ? 9 : (k - 1);
    tb.g[pos] = Gate{0, 9 - ((i + 9) % 10), 9 - i, idx}; ++pos; ++idx;
  }
  return tb;
}
constexpr GateTab GTC = make_gates1();

__device__ __forceinline__ int insert_zero(int v, int p) {
  return ((v >> p) << (p + 1)) | (v & ((1 << p) - 1));
}
__device__ __forceinline__ float2 cmul(float2 A, float2 B) {
  return make_float2(A.x * B.x - A.y * B.y, A.x * B.y + A.y * B.x);
}
__device__ __forceinline__ float2 conj2(float2 A) { return make_float2(A.x, -A.y); }
__device__ __forceinline__ v2f vmk(float x, float y) { v2f r; r.x = x; r.y = y; return r; }

// ---------------- cross-lane xor (DPP / permlane / shfl) ----------------
template<int XM>
__device__ __forceinline__ float lxor(float v) {
  if constexpr (XM == 1) {
    int r = __builtin_amdgcn_update_dpp(__float_as_int(v), __float_as_int(v),
                                        0xB1, 0xF, 0xF, true);
    return __int_as_float(r);
  } else if constexpr (XM == 2) {
    int r = __builtin_amdgcn_update_dpp(__float_as_int(v), __float_as_int(v),
                                        0x4E, 0xF, 0xF, true);
    return __int_as_float(r);
  } else if constexpr (XM == 8) {
    int r = __builtin_amdgcn_update_dpp(__float_as_int(v), __float_as_int(v),
                                        0x128, 0xF, 0xF, true);
    return __int_as_float(r);
  } else if constexpr (XM == 16) {
#if __has_builtin(__builtin_amdgcn_permlane16_swap)
    unsigned uv = __float_as_uint(v);
    auto r = __builtin_amdgcn_permlane16_swap(uv, uv, false, false);
    return __uint_as_float(r[0] ^ r[1] ^ uv);
#else
    return __shfl_xor(v, 16, 64);
#endif
  } else if constexpr (XM == 32) {
#if __has_builtin(__builtin_amdgcn_permlane32_swap)
    unsigned uv = __float_as_uint(v);
    auto r = __builtin_amdgcn_permlane32_swap(uv, uv, false, false);
    return __uint_as_float(r[0] ^ r[1] ^ uv);
#else
    return __shfl_xor(v, 32, 64);
#endif
  } else {
    return __shfl_xor(v, XM, 64);
  }
}
template<int XM>
__device__ __forceinline__ v2f lxor2(v2f v) {
  v2f r; r.x = lxor<XM>(v.x); r.y = lxor<XM>(v.y); return r;
}

__device__ __forceinline__ float wave_sum(float v) {
  v += lxor<1>(v);
  v += lxor<2>(v);
  v += lxor<4>(v);
  v += lxor<8>(v);
  v += lxor<16>(v);
  v += lxor<32>(v);
  return v;
}

// ---------------- per-b group barrier (16 wave-parties) ----------------
struct alignas(128) GBar {
  unsigned cnt;        // barrier wave-arrivals, monotonic
  unsigned gen;        // completed rounds, monotonic
  unsigned done;       // block completions, monotonic
  unsigned pad[29];
};
__device__ GBar g_gb[16];

__device__ __forceinline__ void group_barrier16(int b, int lane) {
  unsigned snap = __hip_atomic_load(&g_gb[b].gen, __ATOMIC_RELAXED, __HIP_MEMORY_SCOPE_AGENT);
  if (lane == 0) {
    unsigned old = __hip_atomic_fetch_add(&g_gb[b].cnt, 1u, __ATOMIC_ACQ_REL,
                                          __HIP_MEMORY_SCOPE_AGENT);
    if ((old & 15u) == 15u)
      __hip_atomic_store(&g_gb[b].gen, snap + 1u, __ATOMIC_RELEASE,
                         __HIP_MEMORY_SCOPE_AGENT);
  }
  while (__hip_atomic_load(&g_gb[b].gen, __ATOMIC_RELAXED, __HIP_MEMORY_SCOPE_AGENT) == snap)
    __builtin_amdgcn_s_sleep(1);
  (void)__hip_atomic_load(&g_gb[b].gen, __ATOMIC_ACQUIRE, __HIP_MEMORY_SCOPE_AGENT);
}

// ---------------- packed register/shuffle gate engine ----------------
template<int P>
__device__ __forceinline__ void ry_gate(v2f (&a)[16], float c, float s, int lane) {
  if constexpr (P < 4) {
    constexpr int m = 1 << P;
#pragma unroll
    for (int r0 = 0; r0 < 16; ++r0) {
      if (!(r0 & m)) {
        int r1 = r0 | m;
        v2f a0 = a[r0], a1 = a[r1];
        a[r0] = c * a0 - s * a1;          // v_pk_mul / v_pk_fma
        a[r1] = s * a0 + c * a1;
      }
    }
  } else {
    constexpr int xm = 1 << (P - 4);
    bool up = (lane >> (P - 4)) & 1;
    float sg = up ? s : -s;
#pragma unroll
    for (int r = 0; r < 16; ++r) {
      v2f wv = lxor2<xm>(a[r]);
      a[r] = c * a[r] + sg * wv;
    }
  }
}

template<int P, int Q>
__device__ __forceinline__ void crx_gate(v2f (&a)[16], float c, float s, int lane) {
  if constexpr (P < 4) {
    constexpr int m = 1 << P;
#pragma unroll
    for (int r0 = 0; r0 < 16; ++r0) {
      if (!(r0 & m)) {
        int r1 = r0 | m;
        bool act;
        if constexpr (Q < 4) act = (r0 >> Q) & 1;   // compile-time folded
        else act = (lane >> (Q - 4)) & 1;
        if (act) {
          v2f a0 = a[r0], a1 = a[r1];
          a[r0] = c * a0 + s * vmk(a1.y, -a1.x);    // v' = c v + (-i s) w
          a[r1] = c * a1 + s * vmk(a0.y, -a0.x);
        }
      }
    }
  } else {
    constexpr int xm = 1 << (P - 4);
#pragma unroll
    for (int r = 0; r < 16; ++r) {
      v2f wv = lxor2<xm>(a[r]);
      bool act;
      if constexpr (Q < 4) act = (r >> Q) & 1;
      else act = (lane >> (Q - 4)) & 1;
      if (act) a[r] = c * a[r] + s * vmk(wv.y, -wv.x);
    }
  }
}

template<bool ADJ, int G>
__device__ __forceinline__ void one_gate(v2f (&a)[16], const float2 (&sc)[40], int lane) {
  constexpr Gate g = GTC.g[ADJ ? (39 - G) : G];
  float2 scv = sc[g.pidx];            // constexpr index -> VGPR
  float s = ADJ ? -scv.x : scv.x;
  float c = scv.y;
  if constexpr (g.ry != 0) ry_gate<g.tbit>(a, c, s, lane);
  else crx_gate<g.tbit, g.cbit>(a, c, s, lane);
}

template<bool ADJ, int... I>
__device__ __forceinline__ void run_layer_impl(v2f (&a)[16], const float2 (&sc)[40],
                                               int lane, std::integer_sequence<int, I...>) {
  (one_gate<ADJ, I>(a, sc, lane), ...);
}

// Preload the 40-entry (sin,cos) table into registers, then run the 40 gates.
template<bool ADJ>
__device__ __forceinline__ void run_layer(v2f (&a)[16], const float2* sc, int lane) {
  float2 rsc[40];
#pragma unroll
  for (int i = 0; i < 40; ++i) rsc[i] = sc[i];
  run_layer_impl<ADJ>(a, rsc, lane, std::make_integer_sequence<int, 40>{});
}

// ---------------- the fused kernel ----------------
__global__ __launch_bounds__(256, 1) void k_fused(const float* __restrict__ x,
                                                  const float* __restrict__ W_fp,
                                                  const float* __restrict__ b_fp,
                                                  const float* __restrict__ prep,
                                                  const float* __restrict__ sig,
                                                  const float* __restrict__ qff,
                                                  const float* __restrict__ W_out,
                                                  const float* __restrict__ b_out,
                                                  float* __restrict__ out,
                                                  float4* __restrict__ part1,
                                                  float4* __restrict__ part2,
                                                  float* __restrict__ sv) {
  int blk = blockIdx.x;
  int b = blk >> 2, sub = blk & 3;
  int tid = threadIdx.x;
  int w = tid >> 6, lane = tid & 63;
  int aa = sub * 4 + w;               // this wave's ancilla column

  __shared__ __align__(16) float h[4][64];   // per-wave feature row (t = aa)
  __shared__ float2 scs[4][80];              // per-wave ts (sin,cos)
  __shared__ float2 qscs[40];
  __shared__ float2 ps[32];                  // prep (sin,cos of th/2)
  __shared__ float2 es[4];                   // e^{i sig_k} = (cos, sin)
  __shared__ float2 u0s[16];                 // u0 = (prepare)|0>_anc
  __shared__ float4 R[2][512];               // 16 KB 2-slot reduction buffer

  // sv zero (ordered before atomics via barrier release chain)
  if (sub == 0 && w == 0 && lane < 30) sv[b * 30 + lane] = 0.f;

  // ---- phase 0a: h row for (b, t=aa); stage small tables ----
  {
    int f = lane, k = f >> 1;
    float div = expf(-(float)(2 * k) * (logf(10000.f) / 64.f));
    float ang = (float)aa * div;
    float pe = (f & 1) ? cosf(ang) : sinf(ang);
    h[w][f] = x[(b * 64 + f) * 16 + aa] + pe;
  }
  if (w == 0) {
    if (lane < 32) {
      float s, c;
      sincosf(0.5f * prep[lane], &s, &c);
      ps[lane] = make_float2(s, c);
    } else if (lane < 36) {
      float s, c;
      sincosf(sig[lane - 32], &s, &c);
      es[lane - 32] = make_float2(c, s);
    }
  } else if (w == 1 && lane < 40) {
    float s, c;
    sincosf(0.5f * qff[lane], &s, &c);
    qscs[lane] = make_float2(s, c);
  }
  __syncthreads();

  // ---- phase 0b: wave 0 builds u0 (16 complex, register evolution) ----
  if (w == 0) {
    float2 v[16];
#pragma unroll
    for (int i = 0; i < 16; ++i) v[i] = make_float2(i == 0 ? 1.f : 0.f, 0.f);
#pragma unroll 1
    for (int ly = 0; ly < 4; ++ly) {
#pragma unroll
      for (int qi = 0; qi < 4; ++qi) {
        int p = 3 - qi;
        float2 rc = ps[ly * 8 + qi * 2 + 0];      // ry
        {
          float s = rc.x, c = rc.y;
#pragma unroll
          for (int m = 0; m < 8; ++m) {
            int a0 = insert_zero(m, p), a1 = a0 | (1 << p);
            float2 t0 = v[a0], t1 = v[a1];
            v[a0] = make_float2(c * t0.x - s * t1.x, c * t0.y - s * t1.y);
            v[a1] = make_float2(s * t0.x + c * t1.x, s * t0.y + c * t1.y);
          }
        }
        rc = ps[ly * 8 + qi * 2 + 1];             // rz
        {
          float s = rc.x, c = rc.y;
#pragma unroll
          for (int m = 0; m < 8; ++m) {
            int a0 = insert_zero(m, p), a1 = a0 | (1 << p);
            float2 t0 = v[a0], t1 = v[a1];
            v[a0] = make_float2(c * t0.x + s * t0.y, c * t0.y - s * t0.x);
            v[a1] = make_float2(c * t1.x - s * t1.y, c * t1.y + s * t1.x);
          }
        }
      }
#pragma unroll
      for (int i = 0; i < 3; ++i) {
        int pc = 3 - i, pt = 2 - i;
#pragma unroll
        for (int m = 0; m < 4; ++m) {
          int mm = insert_zero(m, pt);
          mm = insert_zero(mm, pc);
          int a0 = mm | (1 << pc), a1 = a0 | (1 << pt);
          float2 t0 = v[a0], t1 = v[a1];
          v[a0] = t1; v[a1] = t0;
        }
      }
    }
    if (lane == 0) {
#pragma unroll
      for (int i = 0; i < 16; ++i) u0s[i] = v[i];
    }
  }

  // ---- phase 0c: ts dot products for this wave's column (t = aa) ----
  {
    const float4* h4 = (const float4*)&h[w][0];
    for (int j = lane; j < 80; j += 64) {
      float acc = b_fp[j];
      const float4* w4 = (const float4*)(W_fp + j * 64);
#pragma unroll
      for (int k4 = 0; k4 < 16; ++k4) {
        float4 hh = h4[k4], ww = w4[k4];
        acc += hh.x * ww.x + hh.y * ww.y + hh.z * ww.z + hh.w * ww.w;
      }
      float sg = 1.f / (1.f + expf(-acc));
      float s, c;
      sincosf(sg * 3.14159265358979323846f, &s, &c);   // theta/2 = sigmoid*pi
      scs[w][j] = make_float2(s, c);
    }
  }
  __syncthreads();                     // u0s + scs visible

  float2 u0aa = u0s[aa];
  float2 e0 = es[0], e1 = es[1], e2 = es[2];
  float2 m0  = cmul(u0aa, e0);
  float2 cu0 = conj2(u0aa);
  float2 ceA = conj2(e1);
  float2 wA  = make_float2(-2.f * e1.y * u0aa.y, 2.f * e1.y * u0aa.x);
  float2 ceB = conj2(e2);
  float2 wB  = make_float2(-2.f * e2.y * u0aa.y, 2.f * e2.y * u0aa.x);

  const float2* sc = &scs[w][0];
  v2f a[16];
#pragma unroll
  for (int r = 0; r < 16; ++r) a[r] = vmk(0.f, 0.f);
  if (lane == 0) a[0] = vmk(m0.x, m0.y);

  // ---- 7 layer-passes, ONE fwd body + ONE adj body in the binary ----
  // ph: 0 F sc | 1 F sc+40 | 2 mix1,A sc+40 | 3 A sc | 4 mix2,F sc | 5 F sc+40 | 6 F qscs
#pragma unroll 1
  for (int ph = 0; ph < 7; ++ph) {
    if (ph == 2 || ph == 4) {
      float2 ce = (ph == 2) ? ceA : ceB;
      float2 wk = (ph == 2) ? wA : wB;
      float4* part = (ph == 2) ? part1 : part2;

      // in-block 4->1 reduction of p = cu0 * col into R[0]+R[1]
      __syncthreads();               // R free (prev readers done)
      if (w < 2) {
#pragma unroll
        for (int q = 0; q < 8; ++q) {
          float2 p0 = cmul(cu0, make_float2(a[2 * q].x, a[2 * q].y));
          float2 p1 = cmul(cu0, make_float2(a[2 * q + 1].x, a[2 * q + 1].y));
          R[w][q * 64 + lane] = make_float4(p0.x, p0.y, p1.x, p1.y);
        }
      }
      __syncthreads();
      if (w >= 2) {
#pragma unroll
        for (int q = 0; q < 8; ++q) {
          float4 v = R[w - 2][q * 64 + lane];
          float2 p0 = cmul(cu0, make_float2(a[2 * q].x, a[2 * q].y));
          float2 p1 = cmul(cu0, make_float2(a[2 * q + 1].x, a[2 * q + 1].y));
          R[w - 2][q * 64 + lane] =
              make_float4(v.x + p0.x, v.y + p0.y, v.z + p1.x, v.w + p1.y);
        }
      }
      __syncthreads();
      // block partial (R0+R1) -> global, 2 q-slices per wave, coalesced
#pragma unroll
      for (int qq = 0; qq < 2; ++qq) {
        int q = w * 2 + qq;
        float4 v0 = R[0][q * 64 + lane];
        float4 v1 = R[1][q * 64 + lane];
        part[(size_t)(b * 4 + sub) * 512 + q * 64 + lane] =
            make_float4(v0.x + v1.x, v0.y + v1.y, v0.z + v1.z, v0.w + v1.w);
      }
      group_barrier16(b, lane);      // release covers stores; acquire for reads

      // s = own block partial (LDS) + 3 remote block partials (global)
      float4 s4[8];
#pragma unroll
      for (int q = 0; q < 8; ++q) {
        float4 v0 = R[0][q * 64 + lane];
        float4 v1 = R[1][q * 64 + lane];
        s4[q] = make_float4(v0.x + v1.x, v0.y + v1.y, v0.z + v1.z, v0.w + v1.w);
      }
#pragma unroll 1
      for (int o = 1; o < 4; ++o) {
        int so = (sub + o) & 3;
        const float4* pp = part + (size_t)(b * 4 + so) * 512 + lane;
#pragma unroll
        for (int q = 0; q < 8; ++q) {
          float4 v = pp[q * 64];
          s4[q].x += v.x; s4[q].y += v.y; s4[q].z += v.z; s4[q].w += v.w;
        }
      }
      // col <- ce*col + wk*s
#pragma unroll
      for (int q = 0; q < 8; ++q) {
        v2f a0 = a[2 * q], a1 = a[2 * q + 1];
        a[2 * q] = vmk(ce.x * a0.x - ce.y * a0.y + wk.x * s4[q].x - wk.y * s4[q].y,
                       ce.x * a0.y + ce.y * a0.x + wk.x * s4[q].y + wk.y * s4[q].x);
        a[2 * q + 1] = vmk(ce.x * a1.x - ce.y * a1.y + wk.x * s4[q].z - wk.y * s4[q].w,
                           ce.x * a1.y + ce.y * a1.x + wk.x * s4[q].w + wk.y * s4[q].z);
      }
    }
    const float2* scp;
    if (ph == 6) scp = &qscs[0];
    else scp = sc + ((ph == 1 || ph == 2 || ph == 5) ? 40 : 0);
    if (ph == 2 || ph == 3) run_layer<true>(a, scp, lane);
    else                    run_layer<false>(a, scp, lane);
  }

  // ---- expvals: per-wave obs -> LDS -> block partial -> global sv atomics ----
  {
    float obs[30];
#pragma unroll
    for (int p = 0; p <= 9; ++p) {
      int i = 9 - p;
      float cr = 0.f, ci = 0.f, zz = 0.f;
      if (p < 4) {
        int m = 1 << p;
#pragma unroll
        for (int r0 = 0; r0 < 16; ++r0) {
          if (!(r0 & m)) {
            v2f A0 = a[r0], A1 = a[r0 | m];
            cr += A0.x * A1.x + A0.y * A1.y;
            ci += A0.x * A1.y - A0.y * A1.x;
            zz += (A0.x * A0.x + A0.y * A0.y) - (A1.x * A1.x + A1.y * A1.y);
          }
        }
      } else {
        int xm = 1 << (p - 4);
        bool up = (lane >> (p - 4)) & 1;
#pragma unroll
        for (int r = 0; r < 16; ++r) {
          float wx = __shfl_xor(a[r].x, xm, 64);
          float wy = __shfl_xor(a[r].y, xm, 64);
          float n2 = a[r].x * a[r].x + a[r].y * a[r].y;
          if (!up) {
            cr += a[r].x * wx + a[r].y * wy;
            ci += a[r].x * wy - a[r].y * wx;
            zz += n2;
          } else {
            zz -= n2;
          }
        }
      }
      obs[i] = 2.f * cr;
      obs[10 + i] = 2.f * ci;
      obs[20 + i] = zz;
    }
#pragma unroll
    for (int j = 0; j < 30; ++j) obs[j] = wave_sum(obs[j]);

    float* Rf = (float*)R;
    __syncthreads();                 // everyone done with R (mix 2 reads)
    if (lane == 0) {
#pragma unroll
      for (int j = 0; j < 30; ++j) Rf[w * 30 + j] = obs[j];
    }
    __syncthreads();
    if (w == 0) {
      if (lane < 30) {
        float v = Rf[0 * 30 + lane] + Rf[1 * 30 + lane] +
                  Rf[2 * 30 + lane] + Rf[3 * 30 + lane];
        atomicAdd(&sv[b * 30 + lane], v);
      }
      // last-arriving block of group b computes the output row
      int lastflag = 0;
      if (lane == 0) {
        unsigned old = __hip_atomic_fetch_add(&g_gb[b].done, 1u, __ATOMIC_ACQ_REL,
                                              __HIP_MEMORY_SCOPE_AGENT);
        lastflag = ((old & 3u) == 3u) ? 1 : 0;
      }
      lastflag = __shfl(lastflag, 0, 64);
      if (lastflag) {
        (void)__hip_atomic_load(&g_gb[b].done, __ATOMIC_ACQUIRE, __HIP_MEMORY_SCOPE_AGENT);
        if (lane < 8) {
          float acc = b_out[lane];
#pragma unroll
          for (int j = 0; j < 30; ++j) acc += W_out[lane * 30 + j] * sv[b * 30 + j];
          out[b * 8 + lane] = acc;
        }
      }
    }
  }
}

extern "C" void kernel_launch(void* const* d_in, const int* in_sizes, int n_in,
                              void* d_out, int out_size, void* d_ws, size_t ws_size,
                              hipStream_t stream) {
  const float* x     = (const float*)d_in[0];
  const float* W_fp  = (const float*)d_in[1];
  const float* b_fp  = (const float*)d_in[2];
  const float* prep  = (const float*)d_in[3];
  const float* sig   = (const float*)d_in[4];
  const float* qff   = (const float*)d_in[5];
  const float* W_out = (const float*)d_in[6];
  const float* b_out = (const float*)d_in[7];
  float* out = (float*)d_out;
  (void)in_sizes; (void)n_in; (void)out_size;

  // ws: part1 (512 KB) | part2 (512 KB) | sv (1920 B). Needs ~1.05 MB.
  char* ws = (char*)d_ws;
  const size_t SZ_PART = (size_t)64 * 512 * 16;   // 64 block-partials * 8 KB
  float4* part1 = (float4*)ws;
  float4* part2 = (float4*)(ws + SZ_PART);
  float*  sv    = (float*)(ws + 2 * SZ_PART);
  (void)ws_size;

  k_fused<<<dim3(64), dim3(256), 0, stream>>>(x, W_fp, b_fp, prep, sig, qff,
                                              W_out, b_out, out, part1, part2, sv);
}

// Round 10
// 161.714 us; speedup vs baseline: 1.5440x; 1.0111x over previous
//
#include <hip/hip_runtime.h>
#include <math.h>
#include <utility>

// B=16, T=16, FDIM=64, ODIM=8, NQ=10, NA=4, LAYERS=2, DEGREE=3.
// ROUND 10: each column (b,a) is split across 2 WAVES (512 amps each):
//   n = [lane5:3 | wbit | lane2:0 | r2:0]   (8 v2f regs per thread)
// Grid 128 blocks x 256 thr (4 waves = 2 columns x 2 halves), 1 wave/SIMD.
// Rationale: rounds 5/7/9 all converge to ~900 cyc/gate/wave regardless of
// gate-body micro-structure; round 8 proved the cost is per-wave serial.
// Halving gates/wave is the remaining lever of the right magnitude.
// Gates on bit<3: thread-local. Lane bits: P3/P4->DPP xor1/2, P5->ds_swizzle
// xor4, P7->DPP row_ror:8, P8/P9->permlane16/32_swap. P6 (wave bit): LDS
// exchange, double-buffered, ONE __syncthreads per exchange (28+1 total).
// Rank-1 pcphase mixes (round-5 algebra), Mend deleted (unitary on ancilla).
// Mix: in-block 2-column LDS reduce -> 8KB block partial -> 32-wave-party
// group barrier (monotonic cnt/gen) -> own LDS + 7 remote partials.

typedef float v2f __attribute__((ext_vector_type(2)));

struct Gate { int ry; int tbit; int cbit; int pidx; };
struct GateTab { Gate g[40]; };

constexpr GateTab make_gates1() {
  GateTab tb{};
  int pos = 0, idx = 0;
  for (int i = 0; i < 10; ++i) { tb.g[pos] = Gate{1, 9 - i, -1, idx}; ++pos; ++idx; }
  for (int i = 9; i >= 0; --i) { tb.g[pos] = Gate{0, 9 - ((i + 1) % 10), 9 - i, idx}; ++pos; ++idx; }
  for (int i = 0; i < 10; ++i) { tb.g[pos] = Gate{1, 9 - i, -1, idx}; ++pos; ++idx; }
  for (int k = 0; k < 10; ++k) {
    int i = (k == 0) ? 9 : (k - 1);
    tb.g[pos] = Gate{0, 9 - ((i + 9) % 10), 9 - i, idx}; ++pos; ++idx;
  }
  return tb;
}
constexpr GateTab GTC = make_gates1();

constexpr int lanebit_of(int P) {       // lane-bit index for P in {3,4,5,7,8,9}
  return P == 3 ? 0 : P == 4 ? 1 : P == 5 ? 2 : P == 7 ? 3 : P == 8 ? 4 : 5;
}

__device__ __forceinline__ int insert_zero(int v, int p) {
  return ((v >> p) << (p + 1)) | (v & ((1 << p) - 1));
}
__device__ __forceinline__ float2 cmul(float2 A, float2 B) {
  return make_float2(A.x * B.x - A.y * B.y, A.x * B.y + A.y * B.x);
}
__device__ __forceinline__ float2 conj2(float2 A) { return make_float2(A.x, -A.y); }
__device__ __forceinline__ v2f vmk(float x, float y) { v2f r; r.x = x; r.y = y; return r; }

// ---------------- cross-lane xor (DPP / ds_swizzle / permlane) ----------------
template<int XM>
__device__ __forceinline__ float lxor(float v) {
  if constexpr (XM == 1) {
    int r = __builtin_amdgcn_update_dpp(__float_as_int(v), __float_as_int(v),
                                        0xB1, 0xF, 0xF, true);
    return __int_as_float(r);
  } else if constexpr (XM == 2) {
    int r = __builtin_amdgcn_update_dpp(__float_as_int(v), __float_as_int(v),
                                        0x4E, 0xF, 0xF, true);
    return __int_as_float(r);
  } else if constexpr (XM == 4) {
    int r = __builtin_amdgcn_ds_swizzle(__float_as_int(v), 0x101F);  // xor4
    return __int_as_float(r);
  } else if constexpr (XM == 8) {
    int r = __builtin_amdgcn_update_dpp(__float_as_int(v), __float_as_int(v),
                                        0x128, 0xF, 0xF, true);      // row_ror:8
    return __int_as_float(r);
  } else if constexpr (XM == 16) {
#if __has_builtin(__builtin_amdgcn_permlane16_swap)
    unsigned uv = __float_as_uint(v);
    auto r = __builtin_amdgcn_permlane16_swap(uv, uv, false, false);
    return __uint_as_float(r[0] ^ r[1] ^ uv);
#else
    return __shfl_xor(v, 16, 64);
#endif
  } else {
#if __has_builtin(__builtin_amdgcn_permlane32_swap)
    unsigned uv = __float_as_uint(v);
    auto r = __builtin_amdgcn_permlane32_swap(uv, uv, false, false);
    return __uint_as_float(r[0] ^ r[1] ^ uv);
#else
    return __shfl_xor(v, 32, 64);
#endif
  }
}
template<int XM>
__device__ __forceinline__ v2f lxor2(v2f v) {
  v2f r; r.x = lxor<XM>(v.x); r.y = lxor<XM>(v.y); return r;
}

__device__ __forceinline__ float wave_sum(float v) {
  v += lxor<1>(v);
  v += lxor<2>(v);
  v += lxor<4>(v);
  v += lxor<8>(v);
  v += lxor<16>(v);
  v += lxor<32>(v);
  return v;
}

// ---------------- per-b group barrier (32 wave-parties) ----------------
struct alignas(128) GBar {
  unsigned cnt;        // barrier wave-arrivals, monotonic
  unsigned gen;        // completed rounds, monotonic
  unsigned done;       // block completions, monotonic
  unsigned pad[29];
};
__device__ GBar g_gb[16];

__device__ __forceinline__ void group_barrier32(int b, int lane) {
  unsigned snap = __hip_atomic_load(&g_gb[b].gen, __ATOMIC_RELAXED, __HIP_MEMORY_SCOPE_AGENT);
  if (lane == 0) {
    unsigned old = __hip_atomic_fetch_add(&g_gb[b].cnt, 1u, __ATOMIC_ACQ_REL,
                                          __HIP_MEMORY_SCOPE_AGENT);
    if ((old & 31u) == 31u)
      __hip_atomic_store(&g_gb[b].gen, snap + 1u, __ATOMIC_RELEASE,
                         __HIP_MEMORY_SCOPE_AGENT);
  }
  while (__hip_atomic_load(&g_gb[b].gen, __ATOMIC_RELAXED, __HIP_MEMORY_SCOPE_AGENT) == snap)
    __builtin_amdgcn_s_sleep(1);
  (void)__hip_atomic_load(&g_gb[b].gen, __ATOMIC_ACQUIRE, __HIP_MEMORY_SCOPE_AGENT);
}

// ---------------- gate engine context (wave-split exchange) ----------------
struct Ctx {
  int lane, wbit;
  int buf;                       // double-buffer parity for exchanges
  float2* xo0; float2* xo1;      // own slots (buf 0/1)
  const float2* xp0; const float2* xp1;  // partner slots
};

// Exchange: write own 8 regs, one barrier, return partner pointer; toggle buf.
__device__ __forceinline__ const float2* xchg(v2f (&a)[8], Ctx& ctx) {
  float2* wo = ctx.buf ? ctx.xo1 : ctx.xo0;
#pragma unroll
  for (int r = 0; r < 8; ++r) wo[r] = make_float2(a[r].x, a[r].y);
  __syncthreads();
  const float2* wp = ctx.buf ? ctx.xp1 : ctx.xp0;
  ctx.buf ^= 1;
  return wp;
}

template<int Q>
__device__ __forceinline__ bool act_of(int r, int lane) {
  if constexpr (Q < 3) return (r >> Q) & 1;
  else { constexpr int lb = lanebit_of(Q); return (lane >> lb) & 1; }
}

template<int P>
__device__ __forceinline__ void ry_gate(v2f (&a)[8], float c, float s, Ctx& ctx) {
  if constexpr (P < 3) {
    constexpr int m = 1 << P;
#pragma unroll
    for (int r0 = 0; r0 < 8; ++r0) {
      if (!(r0 & m)) {
        int r1 = r0 | m;
        v2f a0 = a[r0], a1 = a[r1];
        a[r0] = c * a0 - s * a1;
        a[r1] = s * a0 + c * a1;
      }
    }
  } else if constexpr (P == 6) {
    const float2* wp = xchg(a, ctx);
    float sg = ctx.wbit ? s : -s;
#pragma unroll
    for (int r = 0; r < 8; ++r) {
      float2 w = wp[r];
      a[r] = c * a[r] + sg * vmk(w.x, w.y);
    }
  } else {
    constexpr int xm = 1 << lanebit_of(P);
    bool up = (ctx.lane >> lanebit_of(P)) & 1;
    float sg = up ? s : -s;
#pragma unroll
    for (int r = 0; r < 8; ++r) {
      v2f wv = lxor2<xm>(a[r]);
      a[r] = c * a[r] + sg * wv;
    }
  }
}

// unconditional crx rotation on target P (used when control is the wave bit)
template<int P>
__device__ __forceinline__ void crx_all(v2f (&a)[8], float c, float s, Ctx& ctx) {
  if constexpr (P < 3) {
    constexpr int m = 1 << P;
#pragma unroll
    for (int r0 = 0; r0 < 8; ++r0) {
      if (!(r0 & m)) {
        int r1 = r0 | m;
        v2f a0 = a[r0], a1 = a[r1];
        a[r0] = c * a0 + s * vmk(a1.y, -a1.x);
        a[r1] = c * a1 + s * vmk(a0.y, -a0.x);
      }
    }
  } else {
    constexpr int xm = 1 << lanebit_of(P);
#pragma unroll
    for (int r = 0; r < 8; ++r) {
      v2f wv = lxor2<xm>(a[r]);
      a[r] = c * a[r] + s * vmk(wv.y, -wv.x);
    }
  }
}

template<int P, int Q>
__device__ __forceinline__ void crx_gate(v2f (&a)[8], float c, float s, Ctx& ctx) {
  if constexpr (Q == 6) {
    if (ctx.wbit) crx_all<P>(a, c, s, ctx);   // wave-uniform control; no syncs inside
  } else if constexpr (P == 6) {
    const float2* wp = xchg(a, ctx);
#pragma unroll
    for (int r = 0; r < 8; ++r) {
      if (act_of<Q>(r, ctx.lane)) {
        float2 w = wp[r];
        a[r] = c * a[r] + s * vmk(w.y, -w.x);
      }
    }
  } else if constexpr (P < 3) {
    constexpr int m = 1 << P;
#pragma unroll
    for (int r0 = 0; r0 < 8; ++r0) {
      if (!(r0 & m)) {
        int r1 = r0 | m;
        if (act_of<Q>(r0, ctx.lane)) {
          v2f a0 = a[r0], a1 = a[r1];
          a[r0] = c * a0 + s * vmk(a1.y, -a1.x);
          a[r1] = c * a1 + s * vmk(a0.y, -a0.x);
        }
      }
    }
  } else {
    constexpr int xm = 1 << lanebit_of(P);
#pragma unroll
    for (int r = 0; r < 8; ++r) {
      v2f wv = lxor2<xm>(a[r]);
      if (act_of<Q>(r, ctx.lane)) a[r] = c * a[r] + s * vmk(wv.y, -wv.x);
    }
  }
}

template<bool ADJ, int G>
__device__ __forceinline__ void one_gate(v2f (&a)[8], const float2 (&sc)[40], Ctx& ctx) {
  constexpr Gate g = GTC.g[ADJ ? (39 - G) : G];
  float2 scv = sc[g.pidx];
  float s = ADJ ? -scv.x : scv.x;
  float c = scv.y;
  if constexpr (g.ry != 0) ry_gate<g.tbit>(a, c, s, ctx);
  else crx_gate<g.tbit, g.cbit>(a, c, s, ctx);
}

template<bool ADJ, int... I>
__device__ __forceinline__ void run_layer_impl(v2f (&a)[8], const float2 (&sc)[40],
                                               Ctx& ctx, std::integer_sequence<int, I...>) {
  (one_gate<ADJ, I>(a, sc, ctx), ...);
}

template<bool ADJ>
__device__ __forceinline__ void run_layer(v2f (&a)[8], const float2* sc, Ctx& ctx) {
  float2 rsc[40];
#pragma unroll
  for (int i = 0; i < 40; ++i) rsc[i] = sc[i];
  run_layer_impl<ADJ>(a, rsc, ctx, std::make_integer_sequence<int, 40>{});
}

// ---------------- the fused kernel ----------------
__global__ __launch_bounds__(256, 1) void k_fused(const float* __restrict__ x,
                                                  const float* __restrict__ W_fp,
                                                  const float* __restrict__ b_fp,
                                                  const float* __restrict__ prep,
                                                  const float* __restrict__ sig,
                                                  const float* __restrict__ qff,
                                                  const float* __restrict__ W_out,
                                                  const float* __restrict__ b_out,
                                                  float* __restrict__ out,
                                                  float4* __restrict__ part1,
                                                  float4* __restrict__ part2,
                                                  float* __restrict__ sv) {
  int blk = blockIdx.x;
  int b = blk >> 3, sub = blk & 7;
  int tid = threadIdx.x;
  int w = tid >> 6, lane = tid & 63;
  int c = w >> 1, wbit = w & 1;
  int aa = sub * 2 + c;               // this column's ancilla index

  __shared__ float2 X[2][2][2][64][8];       // [c][buf][wbit][lane][r] 32 KB
  __shared__ float2 R[1024];                 // 8 KB partial (layout: wbit*512+lane*8+r)
  __shared__ __align__(16) float h[2][64];
  __shared__ float2 scs[2][80];
  __shared__ float2 qscs[40];
  __shared__ float2 ps[32];
  __shared__ float2 es[4];
  __shared__ float2 u0s[16];

  // sv zero (ordered before final atomics via barrier release chain)
  if (sub == 0 && w == 0 && lane < 30) sv[b * 30 + lane] = 0.f;

  // ---- phase 0a: h rows + small tables ----
  if (wbit == 0) {
    int f = lane, k = f >> 1;
    float div = expf(-(float)(2 * k) * (logf(10000.f) / 64.f));
    float ang = (float)aa * div;
    float pe = (f & 1) ? cosf(ang) : sinf(ang);
    h[c][f] = x[(b * 64 + f) * 16 + aa] + pe;
  }
  if (w == 1) {
    if (lane < 32) {
      float s, cc;
      sincosf(0.5f * prep[lane], &s, &cc);
      ps[lane] = make_float2(s, cc);
    } else if (lane < 36) {
      float s, cc;
      sincosf(sig[lane - 32], &s, &cc);
      es[lane - 32] = make_float2(cc, s);
    }
  } else if (w == 3 && lane < 40) {
    float s, cc;
    sincosf(0.5f * qff[lane], &s, &cc);
    qscs[lane] = make_float2(s, cc);
  }
  __syncthreads();

  // ---- phase 0b: wave 0 builds u0 = (prepare)|0>_anc ----
  if (w == 0) {
    float2 v[16];
#pragma unroll
    for (int i = 0; i < 16; ++i) v[i] = make_float2(i == 0 ? 1.f : 0.f, 0.f);
#pragma unroll 1
    for (int ly = 0; ly < 4; ++ly) {
#pragma unroll
      for (int qi = 0; qi < 4; ++qi) {
        int p = 3 - qi;
        float2 rc = ps[ly * 8 + qi * 2 + 0];      // ry
        {
          float s = rc.x, cc = rc.y;
#pragma unroll
          for (int m = 0; m < 8; ++m) {
            int a0 = insert_zero(m, p), a1 = a0 | (1 << p);
            float2 t0 = v[a0], t1 = v[a1];
            v[a0] = make_float2(cc * t0.x - s * t1.x, cc * t0.y - s * t1.y);
            v[a1] = make_float2(s * t0.x + cc * t1.x, s * t0.y + cc * t1.y);
          }
        }
        rc = ps[ly * 8 + qi * 2 + 1];             // rz
        {
          float s = rc.x, cc = rc.y;
#pragma unroll
          for (int m = 0; m < 8; ++m) {
            int a0 = insert_zero(m, p), a1 = a0 | (1 << p);
            float2 t0 = v[a0], t1 = v[a1];
            v[a0] = make_float2(cc * t0.x + s * t0.y, cc * t0.y - s * t0.x);
            v[a1] = make_float2(cc * t1.x - s * t1.y, cc * t1.y + s * t1.x);
          }
        }
      }
#pragma unroll
      for (int i = 0; i < 3; ++i) {
        int pc = 3 - i, pt = 2 - i;
#pragma unroll
        for (int m = 0; m < 4; ++m) {
          int mm = insert_zero(m, pt);
          mm = insert_zero(mm, pc);
          int a0 = mm | (1 << pc), a1 = a0 | (1 << pt);
          float2 t0 = v[a0], t1 = v[a1];
          v[a0] = t1; v[a1] = t0;
        }
      }
    }
    if (lane == 0) {
#pragma unroll
      for (int i = 0; i < 16; ++i) u0s[i] = v[i];
    }
  }

  // ---- phase 0c: ts dot products (each wave does 40 of its column's 80) ----
  if (lane < 40) {
    int j = wbit * 40 + lane;
    const float4* h4 = (const float4*)&h[c][0];
    float acc = b_fp[j];
    const float4* w4 = (const float4*)(W_fp + j * 64);
#pragma unroll
    for (int k4 = 0; k4 < 16; ++k4) {
      float4 hh = h4[k4], ww = w4[k4];
      acc += hh.x * ww.x + hh.y * ww.y + hh.z * ww.z + hh.w * ww.w;
    }
    float sg = 1.f / (1.f + expf(-acc));
    float s, cc;
    sincosf(sg * 3.14159265358979323846f, &s, &cc);   // theta/2 = sigmoid*pi
    scs[c][j] = make_float2(s, cc);
  }
  __syncthreads();                     // u0s + scs + es visible

  float2 u0aa = u0s[aa];
  float2 e0 = es[0], e1 = es[1], e2 = es[2];
  float2 m0  = cmul(u0aa, e0);
  float2 cu0 = conj2(u0aa);
  float2 ceA = conj2(e1);
  float2 wA  = make_float2(-2.f * e1.y * u0aa.y, 2.f * e1.y * u0aa.x);
  float2 ceB = conj2(e2);
  float2 wB  = make_float2(-2.f * e2.y * u0aa.y, 2.f * e2.y * u0aa.x);

  Ctx ctx;
  ctx.lane = lane; ctx.wbit = wbit; ctx.buf = 0;
  ctx.xo0 = &X[c][0][wbit][lane][0];
  ctx.xo1 = &X[c][1][wbit][lane][0];
  ctx.xp0 = &X[c][0][wbit ^ 1][lane][0];
  ctx.xp1 = &X[c][1][wbit ^ 1][lane][0];

  const float2* sc = &scs[c][0];
  v2f a[8];
#pragma unroll
  for (int r = 0; r < 8; ++r) a[r] = vmk(0.f, 0.f);
  if (wbit == 0 && lane == 0) a[0] = vmk(m0.x, m0.y);   // n = 0

  // ---- 7 layer-passes; mixes before passes 2 and 4 ----
  // ph: 0 F sc | 1 F sc+40 | 2 mix1,A sc+40 | 3 A sc | 4 mix2,F sc | 5 F sc+40 | 6 F qscs
#pragma unroll 1
  for (int ph = 0; ph < 7; ++ph) {
    if (ph == 2 || ph == 4) {
      float2 ce = (ph == 2) ? ceA : ceB;
      float2 wk = (ph == 2) ? wA : wB;
      float4* part = (ph == 2) ? part1 : part2;
      int base = wbit * 512 + lane * 8;

      __syncthreads();               // R free
      if (c == 0) {
#pragma unroll
        for (int r = 0; r < 8; ++r)
          R[base + r] = cmul(cu0, make_float2(a[r].x, a[r].y));
      }
      __syncthreads();
      if (c == 1) {
#pragma unroll
        for (int r = 0; r < 8; ++r) {
          float2 v = R[base + r];
          float2 p = cmul(cu0, make_float2(a[r].x, a[r].y));
          R[base + r] = make_float2(v.x + p.x, v.y + p.y);
        }
      }
      __syncthreads();
      // block partial -> global (512 float4; 2 per thread, coalesced)
      {
        float4* dst = part + (size_t)(b * 8 + sub) * 512;
        const float4* src = (const float4*)R;
        dst[tid] = src[tid];
        dst[tid + 256] = src[tid + 256];
      }
      group_barrier32(b, lane);      // release covers stores; acquire for reads

      // s = own block partial (LDS) + 7 remote block partials (global)
      float4 sA[4];
#pragma unroll
      for (int q = 0; q < 4; ++q) {
        float2 lo = R[base + 2 * q], hi = R[base + 2 * q + 1];
        sA[q] = make_float4(lo.x, lo.y, hi.x, hi.y);
      }
#pragma unroll 1
      for (int o = 1; o < 8; ++o) {
        int so = (sub + o) & 7;
        const float4* pp = part + (size_t)(b * 8 + so) * 512 + wbit * 256 + lane * 4;
#pragma unroll
        for (int q = 0; q < 4; ++q) {
          float4 v = pp[q];
          sA[q].x += v.x; sA[q].y += v.y; sA[q].z += v.z; sA[q].w += v.w;
        }
      }
      // col <- ce*col + wk*s
#pragma unroll
      for (int q = 0; q < 4; ++q) {
        v2f a0 = a[2 * q], a1 = a[2 * q + 1];
        a[2 * q] = vmk(ce.x * a0.x - ce.y * a0.y + wk.x * sA[q].x - wk.y * sA[q].y,
                       ce.x * a0.y + ce.y * a0.x + wk.x * sA[q].y + wk.y * sA[q].x);
        a[2 * q + 1] = vmk(ce.x * a1.x - ce.y * a1.y + wk.x * sA[q].z - wk.y * sA[q].w,
                           ce.x * a1.y + ce.y * a1.x + wk.x * sA[q].w + wk.y * sA[q].z);
      }
    }
    const float2* scp;
    if (ph == 6) scp = &qscs[0];
    else scp = sc + ((ph == 1 || ph == 2 || ph == 5) ? 40 : 0);
    if (ph == 2 || ph == 3) run_layer<true>(a, scp, ctx);
    else                    run_layer<false>(a, scp, ctx);
  }

  // ---- expvals ----
  {
    float obs[30];
#pragma unroll
    for (int p = 0; p <= 9; ++p) {
      int i = 9 - p;
      float cr = 0.f, ci = 0.f, zz = 0.f;
      if (p < 3) {
        int m = 1 << p;
#pragma unroll
        for (int r0 = 0; r0 < 8; ++r0) {
          if (!(r0 & m)) {
            v2f A0 = a[r0], A1 = a[r0 | m];
            cr += A0.x * A1.x + A0.y * A1.y;
            ci += A0.x * A1.y - A0.y * A1.x;
            zz += (A0.x * A0.x + A0.y * A0.y) - (A1.x * A1.x + A1.y * A1.y);
          }
        }
      } else if (p == 6) {
        // cross-wave observable: exchange, low half computes cr/ci
        float2* wo = ctx.buf ? ctx.xo1 : ctx.xo0;
#pragma unroll
        for (int r = 0; r < 8; ++r) wo[r] = make_float2(a[r].x, a[r].y);
        __syncthreads();
        const float2* wp = ctx.buf ? ctx.xp1 : ctx.xp0;
        ctx.buf ^= 1;
#pragma unroll
        for (int r = 0; r < 8; ++r) {
          float n2 = a[r].x * a[r].x + a[r].y * a[r].y;
          if (wbit == 0) {
            float2 ww = wp[r];
            cr += a[r].x * ww.x + a[r].y * ww.y;
            ci += a[r].x * ww.y - a[r].y * ww.x;
            zz += n2;
          } else {
            zz -= n2;
          }
        }
      } else {
        int lb = (p == 3) ? 0 : (p == 4) ? 1 : (p == 5) ? 2 : (p == 7) ? 3 : (p == 8) ? 4 : 5;
        int xm = 1 << lb;
        bool up = (lane >> lb) & 1;
#pragma unroll
        for (int r = 0; r < 8; ++r) {
          float wx = __shfl_xor(a[r].x, xm, 64);
          float wy = __shfl_xor(a[r].y, xm, 64);
          float n2 = a[r].x * a[r].x + a[r].y * a[r].y;
          if (!up) {
            cr += a[r].x * wx + a[r].y * wy;
            ci += a[r].x * wy - a[r].y * wx;
            zz += n2;
          } else {
            zz -= n2;
          }
        }
      }
      obs[i] = 2.f * cr;
      obs[10 + i] = 2.f * ci;
      obs[20 + i] = zz;
    }
#pragma unroll
    for (int j = 0; j < 30; ++j) obs[j] = wave_sum(obs[j]);

    float* Rf = (float*)R;
    __syncthreads();                 // R free (mix-2 gather long done)
    if (lane == 0) {
#pragma unroll
      for (int j = 0; j < 30; ++j) Rf[w * 30 + j] = obs[j];
    }
    __syncthreads();
    if (w == 0) {
      if (lane < 30) {
        float v = Rf[0 * 30 + lane] + Rf[1 * 30 + lane] +
                  Rf[2 * 30 + lane] + Rf[3 * 30 + lane];
        atomicAdd(&sv[b * 30 + lane], v);
      }
      // last-arriving block of group b computes the output row
      int lastflag = 0;
      if (lane == 0) {
        unsigned old = __hip_atomic_fetch_add(&g_gb[b].done, 1u, __ATOMIC_ACQ_REL,
                                              __HIP_MEMORY_SCOPE_AGENT);
        lastflag = ((old & 7u) == 7u) ? 1 : 0;
      }
      lastflag = __shfl(lastflag, 0, 64);
      if (lastflag) {
        (void)__hip_atomic_load(&g_gb[b].done, __ATOMIC_ACQUIRE, __HIP_MEMORY_SCOPE_AGENT);
        if (lane < 8) {
          float acc = b_out[lane];
#pragma unroll
          for (int j = 0; j < 30; ++j) acc += W_out[lane * 30 + j] * sv[b * 30 + j];
          out[b * 8 + lane] = acc;
        }
      }
    }
  }
}

extern "C" void kernel_launch(void* const* d_in, const int* in_sizes, int n_in,
                              void* d_out, int out_size, void* d_ws, size_t ws_size,
                              hipStream_t stream) {
  const float* x     = (const float*)d_in[0];
  const float* W_fp  = (const float*)d_in[1];
  const float* b_fp  = (const float*)d_in[2];
  const float* prep  = (const float*)d_in[3];
  const float* sig   = (const float*)d_in[4];
  const float* qff   = (const float*)d_in[5];
  const float* W_out = (const float*)d_in[6];
  const float* b_out = (const float*)d_in[7];
  float* out = (float*)d_out;
  (void)in_sizes; (void)n_in; (void)out_size;

  // ws: part1 (1 MB) | part2 (1 MB) | sv (1920 B). Needs ~2.1 MB.
  char* ws = (char*)d_ws;
  const size_t SZ_PART = (size_t)128 * 512 * 16;   // 128 block-partials * 8 KB
  float4* part1 = (float4*)ws;
  float4* part2 = (float4*)(ws + SZ_PART);
  float*  sv    = (float*)(ws + 2 * SZ_PART);
  (void)ws_size;

  k_fused<<<dim3(128), dim3(256), 0, stream>>>(x, W_fp, b_fp, prep, sig, qff,
                                               W_out, b_out, out, part1, part2, sv);
}

// Round 11
// 159.870 us; speedup vs baseline: 1.5618x; 1.0115x over previous
//
#include <hip/hip_runtime.h>
#include <math.h>
#include <utility>

// B=16, T=16, FDIM=64, ODIM=8, NQ=10, NA=4, LAYERS=2, DEGREE=3.
// ROUND 11 = round 10 geometry (column split across 2 waves, grid 128 x 256
// thr, 1 wave/SIMD) with two fixes:
//  1. NO rsc[40] register table (80 VGPRs -> was spilled to scratch in every
//     round 5-10; a serial ~600cyc scratch reload in front of every gate is
//     the only candidate matching the invariant ~875 cyc/gate plateau).
//     Gates read sc[g.pidx] directly from LDS at constexpr offsets; the
//     compiler pipelines the ds_read_b64s.
//  2. X/R exchange layouts transposed to [r][lane] (8B/lane stride, 2-way
//     bank aliasing = free) -- round 10's [lane][r] was 64B/lane stride =
//     2.09M conflict cycles.
// Everything else identical to round 10 (passed, 102us):
//   n = [lane5:3 | wbit | lane2:0 | r2:0], 8 v2f regs/thread.
//   P<3 thread-local; P3/4 DPP xor1/2, P5 ds_swizzle xor4, P7 DPP row_ror:8,
//   P8/9 permlane16/32_swap; P6 = LDS exchange (1 __syncthreads each).
//   Rank-1 pcphase mixes; Mend deleted (unitary on ancilla).
//   Mix: in-block LDS reduce -> 8KB block partial -> 32-wave-party barrier
//   (monotonic cnt/gen) -> own LDS + 7 remote partials.

typedef float v2f __attribute__((ext_vector_type(2)));

struct Gate { int ry; int tbit; int cbit; int pidx; };
struct GateTab { Gate g[40]; };

constexpr GateTab make_gates1() {
  GateTab tb{};
  int pos = 0, idx = 0;
  for (int i = 0; i < 10; ++i) { tb.g[pos] = Gate{1, 9 - i, -1, idx}; ++pos; ++idx; }
  for (int i = 9; i >= 0; --i) { tb.g[pos] = Gate{0, 9 - ((i + 1) % 10), 9 - i, idx}; ++pos; ++idx; }
  for (int i = 0; i < 10; ++i) { tb.g[pos] = Gate{1, 9 - i, -1, idx}; ++pos; ++idx; }
  for (int k = 0; k < 10; ++k) {
    int i = (k == 0) ? 9 : (k - 1);
    tb.g[pos] = Gate{0, 9 - ((i + 9) % 10), 9 - i, idx}; ++pos; ++idx;
  }
  return tb;
}
constexpr GateTab GTC = make_gates1();

constexpr int lanebit_of(int P) {       // lane-bit index for P in {3,4,5,7,8,9}
  return P == 3 ? 0 : P == 4 ? 1 : P == 5 ? 2 : P == 7 ? 3 : P == 8 ? 4 : 5;
}

__device__ __forceinline__ int insert_zero(int v, int p) {
  return ((v >> p) << (p + 1)) | (v & ((1 << p) - 1));
}
__device__ __forceinline__ float2 cmul(float2 A, float2 B) {
  return make_float2(A.x * B.x - A.y * B.y, A.x * B.y + A.y * B.x);
}
__device__ __forceinline__ float2 conj2(float2 A) { return make_float2(A.x, -A.y); }
__device__ __forceinline__ v2f vmk(float x, float y) { v2f r; r.x = x; r.y = y; return r; }

// ---------------- cross-lane xor (DPP / ds_swizzle / permlane) ----------------
template<int XM>
__device__ __forceinline__ float lxor(float v) {
  if constexpr (XM == 1) {
    int r = __builtin_amdgcn_update_dpp(__float_as_int(v), __float_as_int(v),
                                        0xB1, 0xF, 0xF, true);
    return __int_as_float(r);
  } else if constexpr (XM == 2) {
    int r = __builtin_amdgcn_update_dpp(__float_as_int(v), __float_as_int(v),
                                        0x4E, 0xF, 0xF, true);
    return __int_as_float(r);
  } else if constexpr (XM == 4) {
    int r = __builtin_amdgcn_ds_swizzle(__float_as_int(v), 0x101F);  // xor4
    return __int_as_float(r);
  } else if constexpr (XM == 8) {
    int r = __builtin_amdgcn_update_dpp(__float_as_int(v), __float_as_int(v),
                                        0x128, 0xF, 0xF, true);      // row_ror:8
    return __int_as_float(r);
  } else if constexpr (XM == 16) {
#if __has_builtin(__builtin_amdgcn_permlane16_swap)
    unsigned uv = __float_as_uint(v);
    auto r = __builtin_amdgcn_permlane16_swap(uv, uv, false, false);
    return __uint_as_float(r[0] ^ r[1] ^ uv);
#else
    return __shfl_xor(v, 16, 64);
#endif
  } else {
#if __has_builtin(__builtin_amdgcn_permlane32_swap)
    unsigned uv = __float_as_uint(v);
    auto r = __builtin_amdgcn_permlane32_swap(uv, uv, false, false);
    return __uint_as_float(r[0] ^ r[1] ^ uv);
#else
    return __shfl_xor(v, 32, 64);
#endif
  }
}
template<int XM>
__device__ __forceinline__ v2f lxor2(v2f v) {
  v2f r; r.x = lxor<XM>(v.x); r.y = lxor<XM>(v.y); return r;
}

__device__ __forceinline__ float wave_sum(float v) {
  v += lxor<1>(v);
  v += lxor<2>(v);
  v += lxor<4>(v);
  v += lxor<8>(v);
  v += lxor<16>(v);
  v += lxor<32>(v);
  return v;
}

// ---------------- per-b group barrier (32 wave-parties) ----------------
struct alignas(128) GBar {
  unsigned cnt;        // barrier wave-arrivals, monotonic
  unsigned gen;        // completed rounds, monotonic
  unsigned done;       // block completions, monotonic
  unsigned pad[29];
};
__device__ GBar g_gb[16];

__device__ __forceinline__ void group_barrier32(int b, int lane) {
  unsigned snap = __hip_atomic_load(&g_gb[b].gen, __ATOMIC_RELAXED, __HIP_MEMORY_SCOPE_AGENT);
  if (lane == 0) {
    unsigned old = __hip_atomic_fetch_add(&g_gb[b].cnt, 1u, __ATOMIC_ACQ_REL,
                                          __HIP_MEMORY_SCOPE_AGENT);
    if ((old & 31u) == 31u)
      __hip_atomic_store(&g_gb[b].gen, snap + 1u, __ATOMIC_RELEASE,
                         __HIP_MEMORY_SCOPE_AGENT);
  }
  while (__hip_atomic_load(&g_gb[b].gen, __ATOMIC_RELAXED, __HIP_MEMORY_SCOPE_AGENT) == snap)
    __builtin_amdgcn_s_sleep(1);
  (void)__hip_atomic_load(&g_gb[b].gen, __ATOMIC_ACQUIRE, __HIP_MEMORY_SCOPE_AGENT);
}

// ---------------- gate engine context (wave-split exchange) ----------------
// X layout: [c][buf][wbit][r][lane] -> per-lane stride 8B (2-way bank, free)
struct Ctx {
  int lane, wbit;
  int buf;                       // double-buffer parity for exchanges
  float2* xo0; float2* xo1;      // own slots (buf 0/1), element stride 64
  const float2* xp0; const float2* xp1;  // partner slots
};

// Exchange: write own 8 regs, one barrier, return partner pointer; toggle buf.
__device__ __forceinline__ const float2* xchg(v2f (&a)[8], Ctx& ctx) {
  float2* wo = ctx.buf ? ctx.xo1 : ctx.xo0;
#pragma unroll
  for (int r = 0; r < 8; ++r) wo[r * 64] = make_float2(a[r].x, a[r].y);
  __syncthreads();
  const float2* wp = ctx.buf ? ctx.xp1 : ctx.xp0;
  ctx.buf ^= 1;
  return wp;
}

template<int Q>
__device__ __forceinline__ bool act_of(int r, int lane) {
  if constexpr (Q < 3) return (r >> Q) & 1;
  else { constexpr int lb = lanebit_of(Q); return (lane >> lb) & 1; }
}

template<int P>
__device__ __forceinline__ void ry_gate(v2f (&a)[8], float c, float s, Ctx& ctx) {
  if constexpr (P < 3) {
    constexpr int m = 1 << P;
#pragma unroll
    for (int r0 = 0; r0 < 8; ++r0) {
      if (!(r0 & m)) {
        int r1 = r0 | m;
        v2f a0 = a[r0], a1 = a[r1];
        a[r0] = c * a0 - s * a1;
        a[r1] = s * a0 + c * a1;
      }
    }
  } else if constexpr (P == 6) {
    const float2* wp = xchg(a, ctx);
    float sg = ctx.wbit ? s : -s;
#pragma unroll
    for (int r = 0; r < 8; ++r) {
      float2 w = wp[r * 64];
      a[r] = c * a[r] + sg * vmk(w.x, w.y);
    }
  } else {
    constexpr int xm = 1 << lanebit_of(P);
    bool up = (ctx.lane >> lanebit_of(P)) & 1;
    float sg = up ? s : -s;
#pragma unroll
    for (int r = 0; r < 8; ++r) {
      v2f wv = lxor2<xm>(a[r]);
      a[r] = c * a[r] + sg * wv;
    }
  }
}

// unconditional crx rotation on target P (used when control is the wave bit)
template<int P>
__device__ __forceinline__ void crx_all(v2f (&a)[8], float c, float s, Ctx& ctx) {
  if constexpr (P < 3) {
    constexpr int m = 1 << P;
#pragma unroll
    for (int r0 = 0; r0 < 8; ++r0) {
      if (!(r0 & m)) {
        int r1 = r0 | m;
        v2f a0 = a[r0], a1 = a[r1];
        a[r0] = c * a0 + s * vmk(a1.y, -a1.x);
        a[r1] = c * a1 + s * vmk(a0.y, -a0.x);
      }
    }
  } else {
    constexpr int xm = 1 << lanebit_of(P);
#pragma unroll
    for (int r = 0; r < 8; ++r) {
      v2f wv = lxor2<xm>(a[r]);
      a[r] = c * a[r] + s * vmk(wv.y, -wv.x);
    }
  }
}

template<int P, int Q>
__device__ __forceinline__ void crx_gate(v2f (&a)[8], float c, float s, Ctx& ctx) {
  if constexpr (Q == 6) {
    if (ctx.wbit) crx_all<P>(a, c, s, ctx);   // wave-uniform control; no syncs inside
  } else if constexpr (P == 6) {
    const float2* wp = xchg(a, ctx);
#pragma unroll
    for (int r = 0; r < 8; ++r) {
      if (act_of<Q>(r, ctx.lane)) {
        float2 w = wp[r * 64];
        a[r] = c * a[r] + s * vmk(w.y, -w.x);
      }
    }
  } else if constexpr (P < 3) {
    constexpr int m = 1 << P;
#pragma unroll
    for (int r0 = 0; r0 < 8; ++r0) {
      if (!(r0 & m)) {
        int r1 = r0 | m;
        if (act_of<Q>(r0, ctx.lane)) {
          v2f a0 = a[r0], a1 = a[r1];
          a[r0] = c * a0 + s * vmk(a1.y, -a1.x);
          a[r1] = c * a1 + s * vmk(a0.y, -a0.x);
        }
      }
    }
  } else {
    constexpr int xm = 1 << lanebit_of(P);
#pragma unroll
    for (int r = 0; r < 8; ++r) {
      v2f wv = lxor2<xm>(a[r]);
      if (act_of<Q>(r, ctx.lane)) a[r] = c * a[r] + s * vmk(wv.y, -wv.x);
    }
  }
}

// Direct LDS read of the gate's (sin,cos): constexpr offset from sc base ->
// compiler pipelines the ds_read_b64s; NO 80-VGPR table to spill.
template<bool ADJ, int G>
__device__ __forceinline__ void one_gate(v2f (&a)[8], const float2* sc, Ctx& ctx) {
  constexpr Gate g = GTC.g[ADJ ? (39 - G) : G];
  float2 scv = sc[g.pidx];
  float s = ADJ ? -scv.x : scv.x;
  float c = scv.y;
  if constexpr (g.ry != 0) ry_gate<g.tbit>(a, c, s, ctx);
  else crx_gate<g.tbit, g.cbit>(a, c, s, ctx);
}

template<bool ADJ, int... I>
__device__ __forceinline__ void run_layer_impl(v2f (&a)[8], const float2* sc,
                                               Ctx& ctx, std::integer_sequence<int, I...>) {
  (one_gate<ADJ, I>(a, sc, ctx), ...);
}

template<bool ADJ>
__device__ __forceinline__ void run_layer(v2f (&a)[8], const float2* sc, Ctx& ctx) {
  run_layer_impl<ADJ>(a, sc, ctx, std::make_integer_sequence<int, 40>{});
}

// ---------------- the fused kernel ----------------
__global__ __launch_bounds__(256, 1) void k_fused(const float* __restrict__ x,
                                                  const float* __restrict__ W_fp,
                                                  const float* __restrict__ b_fp,
                                                  const float* __restrict__ prep,
                                                  const float* __restrict__ sig,
                                                  const float* __restrict__ qff,
                                                  const float* __restrict__ W_out,
                                                  const float* __restrict__ b_out,
                                                  float* __restrict__ out,
                                                  float4* __restrict__ part1,
                                                  float4* __restrict__ part2,
                                                  float* __restrict__ sv) {
  int blk = blockIdx.x;
  int b = blk >> 3, sub = blk & 7;
  int tid = threadIdx.x;
  int w = tid >> 6, lane = tid & 63;
  int c = w >> 1, wbit = w & 1;
  int aa = sub * 2 + c;               // this column's ancilla index

  __shared__ float2 X[2][2][2][8][64];       // [c][buf][wbit][r][lane] 16 KB
  __shared__ __align__(16) float2 R2[1024];  // 8 KB partial [wbit][r][lane]
  __shared__ __align__(16) float h[2][64];
  __shared__ float2 scs[2][80];
  __shared__ float2 qscs[40];
  __shared__ float2 ps[32];
  __shared__ float2 es[4];
  __shared__ float2 u0s[16];

  // sv zero (ordered before final atomics via barrier release chain)
  if (sub == 0 && w == 0 && lane < 30) sv[b * 30 + lane] = 0.f;

  // ---- phase 0a: h rows + small tables ----
  if (wbit == 0) {
    int f = lane, k = f >> 1;
    float div = expf(-(float)(2 * k) * (logf(10000.f) / 64.f));
    float ang = (float)aa * div;
    float pe = (f & 1) ? cosf(ang) : sinf(ang);
    h[c][f] = x[(b * 64 + f) * 16 + aa] + pe;
  }
  if (w == 1) {
    if (lane < 32) {
      float s, cc;
      sincosf(0.5f * prep[lane], &s, &cc);
      ps[lane] = make_float2(s, cc);
    } else if (lane < 36) {
      float s, cc;
      sincosf(sig[lane - 32], &s, &cc);
      es[lane - 32] = make_float2(cc, s);
    }
  } else if (w == 3 && lane < 40) {
    float s, cc;
    sincosf(0.5f * qff[lane], &s, &cc);
    qscs[lane] = make_float2(s, cc);
  }
  __syncthreads();

  // ---- phase 0b: wave 0 builds u0 = (prepare)|0>_anc ----
  if (w == 0) {
    float2 v[16];
#pragma unroll
    for (int i = 0; i < 16; ++i) v[i] = make_float2(i == 0 ? 1.f : 0.f, 0.f);
#pragma unroll 1
    for (int ly = 0; ly < 4; ++ly) {
#pragma unroll
      for (int qi = 0; qi < 4; ++qi) {
        int p = 3 - qi;
        float2 rc = ps[ly * 8 + qi * 2 + 0];      // ry
        {
          float s = rc.x, cc = rc.y;
#pragma unroll
          for (int m = 0; m < 8; ++m) {
            int a0 = insert_zero(m, p), a1 = a0 | (1 << p);
            float2 t0 = v[a0], t1 = v[a1];
            v[a0] = make_float2(cc * t0.x - s * t1.x, cc * t0.y - s * t1.y);
            v[a1] = make_float2(s * t0.x + cc * t1.x, s * t0.y + cc * t1.y);
          }
        }
        rc = ps[ly * 8 + qi * 2 + 1];             // rz
        {
          float s = rc.x, cc = rc.y;
#pragma unroll
          for (int m = 0; m < 8; ++m) {
            int a0 = insert_zero(m, p), a1 = a0 | (1 << p);
            float2 t0 = v[a0], t1 = v[a1];
            v[a0] = make_float2(cc * t0.x + s * t0.y, cc * t0.y - s * t0.x);
            v[a1] = make_float2(cc * t1.x - s * t1.y, cc * t1.y + s * t1.x);
          }
        }
      }
#pragma unroll
      for (int i = 0; i < 3; ++i) {
        int pc = 3 - i, pt = 2 - i;
#pragma unroll
        for (int m = 0; m < 4; ++m) {
          int mm = insert_zero(m, pt);
          mm = insert_zero(mm, pc);
          int a0 = mm | (1 << pc), a1 = a0 | (1 << pt);
          float2 t0 = v[a0], t1 = v[a1];
          v[a0] = t1; v[a1] = t0;
        }
      }
    }
    if (lane == 0) {
#pragma unroll
      for (int i = 0; i < 16; ++i) u0s[i] = v[i];
    }
  }

  // ---- phase 0c: ts dot products (each wave does 40 of its column's 80) ----
  if (lane < 40) {
    int j = wbit * 40 + lane;
    const float4* h4 = (const float4*)&h[c][0];
    float acc = b_fp[j];
    const float4* w4 = (const float4*)(W_fp + j * 64);
#pragma unroll
    for (int k4 = 0; k4 < 16; ++k4) {
      float4 hh = h4[k4], ww = w4[k4];
      acc += hh.x * ww.x + hh.y * ww.y + hh.z * ww.z + hh.w * ww.w;
    }
    float sg = 1.f / (1.f + expf(-acc));
    float s, cc;
    sincosf(sg * 3.14159265358979323846f, &s, &cc);   // theta/2 = sigmoid*pi
    scs[c][j] = make_float2(s, cc);
  }
  __syncthreads();                     // u0s + scs + es visible

  float2 u0aa = u0s[aa];
  float2 e0 = es[0], e1 = es[1], e2 = es[2];
  float2 m0  = cmul(u0aa, e0);
  float2 cu0 = conj2(u0aa);
  float2 ceA = conj2(e1);
  float2 wA  = make_float2(-2.f * e1.y * u0aa.y, 2.f * e1.y * u0aa.x);
  float2 ceB = conj2(e2);
  float2 wB  = make_float2(-2.f * e2.y * u0aa.y, 2.f * e2.y * u0aa.x);

  Ctx ctx;
  ctx.lane = lane; ctx.wbit = wbit; ctx.buf = 0;
  ctx.xo0 = &X[c][0][wbit][0][lane];
  ctx.xo1 = &X[c][1][wbit][0][lane];
  ctx.xp0 = &X[c][0][wbit ^ 1][0][lane];
  ctx.xp1 = &X[c][1][wbit ^ 1][0][lane];

  const float2* sc = &scs[c][0];
  v2f a[8];
#pragma unroll
  for (int r = 0; r < 8; ++r) a[r] = vmk(0.f, 0.f);
  if (wbit == 0 && lane == 0) a[0] = vmk(m0.x, m0.y);   // n = 0

  // ---- 7 layer-passes; mixes before passes 2 and 4 ----
  // ph: 0 F sc | 1 F sc+40 | 2 mix1,A sc+40 | 3 A sc | 4 mix2,F sc | 5 F sc+40 | 6 F qscs
#pragma unroll 1
  for (int ph = 0; ph < 7; ++ph) {
    if (ph == 2 || ph == 4) {
      float2 ce = (ph == 2) ? ceA : ceB;
      float2 wk = (ph == 2) ? wA : wB;
      float4* part = (ph == 2) ? part1 : part2;
      int base = wbit * 512 + lane;    // [wbit][r][lane], element stride 64

      __syncthreads();               // R2 free
      if (c == 0) {
#pragma unroll
        for (int r = 0; r < 8; ++r)
          R2[base + r * 64] = cmul(cu0, make_float2(a[r].x, a[r].y));
      }
      __syncthreads();
      if (c == 1) {
#pragma unroll
        for (int r = 0; r < 8; ++r) {
          float2 v = R2[base + r * 64];
          float2 p = cmul(cu0, make_float2(a[r].x, a[r].y));
          R2[base + r * 64] = make_float2(v.x + p.x, v.y + p.y);
        }
      }
      __syncthreads();
      // block partial -> global (linear byte copy; 512 float4, 2/thread)
      {
        float4* dst = part + (size_t)(b * 8 + sub) * 512;
        const float4* src = (const float4*)R2;
        dst[tid] = src[tid];
        dst[tid + 256] = src[tid + 256];
      }
      group_barrier32(b, lane);      // release covers stores; acquire for reads

      // s = own block partial (LDS) + 7 remote block partials (global)
      float2 s2[8];
#pragma unroll
      for (int r = 0; r < 8; ++r) s2[r] = R2[base + r * 64];
#pragma unroll 1
      for (int o = 1; o < 8; ++o) {
        int so = (sub + o) & 7;
        const float2* pp = (const float2*)(part + (size_t)(b * 8 + so) * 512);
#pragma unroll
        for (int r = 0; r < 8; ++r) {
          float2 v = pp[base + r * 64];
          s2[r].x += v.x; s2[r].y += v.y;
        }
      }
      // col <- ce*col + wk*s
#pragma unroll
      for (int r = 0; r < 8; ++r) {
        v2f a0 = a[r];
        a[r] = vmk(ce.x * a0.x - ce.y * a0.y + wk.x * s2[r].x - wk.y * s2[r].y,
                   ce.x * a0.y + ce.y * a0.x + wk.x * s2[r].y + wk.y * s2[r].x);
      }
    }
    const float2* scp;
    if (ph == 6) scp = &qscs[0];
    else scp = sc + ((ph == 1 || ph == 2 || ph == 5) ? 40 : 0);
    if (ph == 2 || ph == 3) run_layer<true>(a, scp, ctx);
    else                    run_layer<false>(a, scp, ctx);
  }

  // ---- expvals ----
  {
    float obs[30];
#pragma unroll
    for (int p = 0; p <= 9; ++p) {
      int i = 9 - p;
      float cr = 0.f, ci = 0.f, zz = 0.f;
      if (p < 3) {
        int m = 1 << p;
#pragma unroll
        for (int r0 = 0; r0 < 8; ++r0) {
          if (!(r0 & m)) {
            v2f A0 = a[r0], A1 = a[r0 | m];
            cr += A0.x * A1.x + A0.y * A1.y;
            ci += A0.x * A1.y - A0.y * A1.x;
            zz += (A0.x * A0.x + A0.y * A0.y) - (A1.x * A1.x + A1.y * A1.y);
          }
        }
      } else if (p == 6) {
        // cross-wave observable: exchange, low half computes cr/ci
        float2* wo = ctx.buf ? ctx.xo1 : ctx.xo0;
#pragma unroll
        for (int r = 0; r < 8; ++r) wo[r * 64] = make_float2(a[r].x, a[r].y);
        __syncthreads();
        const float2* wp = ctx.buf ? ctx.xp1 : ctx.xp0;
        ctx.buf ^= 1;
#pragma unroll
        for (int r = 0; r < 8; ++r) {
          float n2 = a[r].x * a[r].x + a[r].y * a[r].y;
          if (wbit == 0) {
            float2 ww = wp[r * 64];
            cr += a[r].x * ww.x + a[r].y * ww.y;
            ci += a[r].x * ww.y - a[r].y * ww.x;
            zz += n2;
          } else {
            zz -= n2;
          }
        }
      } else {
        int lb = (p == 3) ? 0 : (p == 4) ? 1 : (p == 5) ? 2 : (p == 7) ? 3 : (p == 8) ? 4 : 5;
        int xm = 1 << lb;
        bool up = (lane >> lb) & 1;
#pragma unroll
        for (int r = 0; r < 8; ++r) {
          float wx = __shfl_xor(a[r].x, xm, 64);
          float wy = __shfl_xor(a[r].y, xm, 64);
          float n2 = a[r].x * a[r].x + a[r].y * a[r].y;
          if (!up) {
            cr += a[r].x * wx + a[r].y * wy;
            ci += a[r].x * wy - a[r].y * wx;
            zz += n2;
          } else {
            zz -= n2;
          }
        }
      }
      obs[i] = 2.f * cr;
      obs[10 + i] = 2.f * ci;
      obs[20 + i] = zz;
    }
#pragma unroll
    for (int j = 0; j < 30; ++j) obs[j] = wave_sum(obs[j]);

    float* Rf = (float*)R2;
    __syncthreads();                 // R2 free (mix-2 gather long done)
    if (lane == 0) {
#pragma unroll
      for (int j = 0; j < 30; ++j) Rf[w * 30 + j] = obs[j];
    }
    __syncthreads();
    if (w == 0) {
      if (lane < 30) {
        float v = Rf[0 * 30 + lane] + Rf[1 * 30 + lane] +
                  Rf[2 * 30 + lane] + Rf[3 * 30 + lane];
        atomicAdd(&sv[b * 30 + lane], v);
      }
      // last-arriving block of group b computes the output row
      int lastflag = 0;
      if (lane == 0) {
        unsigned old = __hip_atomic_fetch_add(&g_gb[b].done, 1u, __ATOMIC_ACQ_REL,
                                              __HIP_MEMORY_SCOPE_AGENT);
        lastflag = ((old & 7u) == 7u) ? 1 : 0;
      }
      lastflag = __shfl(lastflag, 0, 64);
      if (lastflag) {
        (void)__hip_atomic_load(&g_gb[b].done, __ATOMIC_ACQUIRE, __HIP_MEMORY_SCOPE_AGENT);
        if (lane < 8) {
          float acc = b_out[lane];
#pragma unroll
          for (int j = 0; j < 30; ++j) acc += W_out[lane * 30 + j] * sv[b * 30 + j];
          out[b * 8 + lane] = acc;
        }
      }
    }
  }
}

extern "C" void kernel_launch(void* const* d_in, const int* in_sizes, int n_in,
                              void* d_out, int out_size, void* d_ws, size_t ws_size,
                              hipStream_t stream) {
  const float* x     = (const float*)d_in[0];
  const float* W_fp  = (const float*)d_in[1];
  const float* b_fp  = (const float*)d_in[2];
  const float* prep  = (const float*)d_in[3];
  const float* sig   = (const float*)d_in[4];
  const float* qff   = (const float*)d_in[5];
  const float* W_out = (const float*)d_in[6];
  const float* b_out = (const float*)d_in[7];
  float* out = (float*)d_out;
  (void)in_sizes; (void)n_in; (void)out_size;

  // ws: part1 (1 MB) | part2 (1 MB) | sv (1920 B). Needs ~2.1 MB.
  char* ws = (char*)d_ws;
  const size_t SZ_PART = (size_t)128 * 512 * 16;   // 128 block-partials * 8 KB
  float4* part1 = (float4*)ws;
  float4* part2 = (float4*)(ws + SZ_PART);
  float*  sv    = (float*)(ws + 2 * SZ_PART);
  (void)ws_size;

  k_fused<<<dim3(128), dim3(256), 0, stream>>>(x, W_fp, b_fp, prep, sig, qff,
                                               W_out, b_out, out, part1, part2, sv);
}

// Round 12
// 149.908 us; speedup vs baseline: 1.6656x; 1.0665x over previous
//
#include <hip/hip_runtime.h>
#include <math.h>
#include <utility>

// B=16, T=16, FDIM=64, ODIM=8, NQ=10, NA=4, LAYERS=2, DEGREE=3.
// ROUND 12 = round 11 (97.5us) + XCD-locality for the b-group:
//  1. Block remap blk = sub*16 + b  (was b*8+sub): all 8 blocks of group b
//     share blk%8 = b%8 -> SAME XCD (dispatch->XCD is round-robin %8 on
//     MI355X; heuristic only, correctness-neutral). Group-barrier RMWs and
//     remote-partial reads become XCD-local L2 (~200cyc vs ~800-900 fabric).
//  2. Remote-partial gather fully unrolled: 7 remotes x 8 loads all in
//     flight -> one latency instead of 8 dependent batches.
//  3. GBar padded to 256B to spread the 16 barrier words across channels.
// Everything else identical to round 11:
//   column split across 2 waves (n = [lane5:3|wbit|lane2:0|r2:0], 8 v2f/thr),
//   grid 128 x 256thr, 1 wave/SIMD; sc read per-gate from LDS (constexpr
//   offsets); X/R in [r][lane] layout (2-way bank aliasing, free);
//   rank-1 pcphase mixes, Mend deleted (unitary on ancilla).

typedef float v2f __attribute__((ext_vector_type(2)));

struct Gate { int ry; int tbit; int cbit; int pidx; };
struct GateTab { Gate g[40]; };

constexpr GateTab make_gates1() {
  GateTab tb{};
  int pos = 0, idx = 0;
  for (int i = 0; i < 10; ++i) { tb.g[pos] = Gate{1, 9 - i, -1, idx}; ++pos; ++idx; }
  for (int i = 9; i >= 0; --i) { tb.g[pos] = Gate{0, 9 - ((i + 1) % 10), 9 - i, idx}; ++pos; ++idx; }
  for (int i = 0; i < 10; ++i) { tb.g[pos] = Gate{1, 9 - i, -1, idx}; ++pos; ++idx; }
  for (int k = 0; k < 10; ++k) {
    int i = (k == 0) ? 9 : (k - 1);
    tb.g[pos] = Gate{0, 9 - ((i + 9) % 10), 9 - i, idx}; ++pos; ++idx;
  }
  return tb;
}
constexpr GateTab GTC = make_gates1();

constexpr int lanebit_of(int P) {       // lane-bit index for P in {3,4,5,7,8,9}
  return P == 3 ? 0 : P == 4 ? 1 : P == 5 ? 2 : P == 7 ? 3 : P == 8 ? 4 : 5;
}

__device__ __forceinline__ int insert_zero(int v, int p) {
  return ((v >> p) << (p + 1)) | (v & ((1 << p) - 1));
}
__device__ __forceinline__ float2 cmul(float2 A, float2 B) {
  return make_float2(A.x * B.x - A.y * B.y, A.x * B.y + A.y * B.x);
}
__device__ __forceinline__ float2 conj2(float2 A) { return make_float2(A.x, -A.y); }
__device__ __forceinline__ v2f vmk(float x, float y) { v2f r; r.x = x; r.y = y; return r; }

// ---------------- cross-lane xor (DPP / ds_swizzle / permlane) ----------------
template<int XM>
__device__ __forceinline__ float lxor(float v) {
  if constexpr (XM == 1) {
    int r = __builtin_amdgcn_update_dpp(__float_as_int(v), __float_as_int(v),
                                        0xB1, 0xF, 0xF, true);
    return __int_as_float(r);
  } else if constexpr (XM == 2) {
    int r = __builtin_amdgcn_update_dpp(__float_as_int(v), __float_as_int(v),
                                        0x4E, 0xF, 0xF, true);
    return __int_as_float(r);
  } else if constexpr (XM == 4) {
    int r = __builtin_amdgcn_ds_swizzle(__float_as_int(v), 0x101F);  // xor4
    return __int_as_float(r);
  } else if constexpr (XM == 8) {
    int r = __builtin_amdgcn_update_dpp(__float_as_int(v), __float_as_int(v),
                                        0x128, 0xF, 0xF, true);      // row_ror:8
    return __int_as_float(r);
  } else if constexpr (XM == 16) {
#if __has_builtin(__builtin_amdgcn_permlane16_swap)
    unsigned uv = __float_as_uint(v);
    auto r = __builtin_amdgcn_permlane16_swap(uv, uv, false, false);
    return __uint_as_float(r[0] ^ r[1] ^ uv);
#else
    return __shfl_xor(v, 16, 64);
#endif
  } else {
#if __has_builtin(__builtin_amdgcn_permlane32_swap)
    unsigned uv = __float_as_uint(v);
    auto r = __builtin_amdgcn_permlane32_swap(uv, uv, false, false);
    return __uint_as_float(r[0] ^ r[1] ^ uv);
#else
    return __shfl_xor(v, 32, 64);
#endif
  }
}
template<int XM>
__device__ __forceinline__ v2f lxor2(v2f v) {
  v2f r; r.x = lxor<XM>(v.x); r.y = lxor<XM>(v.y); return r;
}

__device__ __forceinline__ float wave_sum(float v) {
  v += lxor<1>(v);
  v += lxor<2>(v);
  v += lxor<4>(v);
  v += lxor<8>(v);
  v += lxor<16>(v);
  v += lxor<32>(v);
  return v;
}

// ---------------- per-b group barrier (32 wave-parties, XCD-local) ----------
struct alignas(256) GBar {
  unsigned cnt;        // barrier wave-arrivals, monotonic
  unsigned gen;        // completed rounds, monotonic
  unsigned done;       // block completions, monotonic
  unsigned pad[61];
};
__device__ GBar g_gb[16];

__device__ __forceinline__ void group_barrier32(int b, int lane) {
  unsigned snap = __hip_atomic_load(&g_gb[b].gen, __ATOMIC_RELAXED, __HIP_MEMORY_SCOPE_AGENT);
  if (lane == 0) {
    unsigned old = __hip_atomic_fetch_add(&g_gb[b].cnt, 1u, __ATOMIC_ACQ_REL,
                                          __HIP_MEMORY_SCOPE_AGENT);
    if ((old & 31u) == 31u)
      __hip_atomic_store(&g_gb[b].gen, snap + 1u, __ATOMIC_RELEASE,
                         __HIP_MEMORY_SCOPE_AGENT);
  }
  while (__hip_atomic_load(&g_gb[b].gen, __ATOMIC_RELAXED, __HIP_MEMORY_SCOPE_AGENT) == snap)
    __builtin_amdgcn_s_sleep(1);
  (void)__hip_atomic_load(&g_gb[b].gen, __ATOMIC_ACQUIRE, __HIP_MEMORY_SCOPE_AGENT);
}

// ---------------- gate engine context (wave-split exchange) ----------------
// X layout: [c][buf][wbit][r][lane] -> per-lane stride 8B (2-way bank, free)
struct Ctx {
  int lane, wbit;
  int buf;                       // double-buffer parity for exchanges
  float2* xo0; float2* xo1;      // own slots (buf 0/1), element stride 64
  const float2* xp0; const float2* xp1;  // partner slots
};

// Exchange: write own 8 regs, one barrier, return partner pointer; toggle buf.
__device__ __forceinline__ const float2* xchg(v2f (&a)[8], Ctx& ctx) {
  float2* wo = ctx.buf ? ctx.xo1 : ctx.xo0;
#pragma unroll
  for (int r = 0; r < 8; ++r) wo[r * 64] = make_float2(a[r].x, a[r].y);
  __syncthreads();
  const float2* wp = ctx.buf ? ctx.xp1 : ctx.xp0;
  ctx.buf ^= 1;
  return wp;
}

template<int Q>
__device__ __forceinline__ bool act_of(int r, int lane) {
  if constexpr (Q < 3) return (r >> Q) & 1;
  else { constexpr int lb = lanebit_of(Q); return (lane >> lb) & 1; }
}

template<int P>
__device__ __forceinline__ void ry_gate(v2f (&a)[8], float c, float s, Ctx& ctx) {
  if constexpr (P < 3) {
    constexpr int m = 1 << P;
#pragma unroll
    for (int r0 = 0; r0 < 8; ++r0) {
      if (!(r0 & m)) {
        int r1 = r0 | m;
        v2f a0 = a[r0], a1 = a[r1];
        a[r0] = c * a0 - s * a1;
        a[r1] = s * a0 + c * a1;
      }
    }
  } else if constexpr (P == 6) {
    const float2* wp = xchg(a, ctx);
    float sg = ctx.wbit ? s : -s;
#pragma unroll
    for (int r = 0; r < 8; ++r) {
      float2 w = wp[r * 64];
      a[r] = c * a[r] + sg * vmk(w.x, w.y);
    }
  } else {
    constexpr int xm = 1 << lanebit_of(P);
    bool up = (ctx.lane >> lanebit_of(P)) & 1;
    float sg = up ? s : -s;
#pragma unroll
    for (int r = 0; r < 8; ++r) {
      v2f wv = lxor2<xm>(a[r]);
      a[r] = c * a[r] + sg * wv;
    }
  }
}

// unconditional crx rotation on target P (used when control is the wave bit)
template<int P>
__device__ __forceinline__ void crx_all(v2f (&a)[8], float c, float s, Ctx& ctx) {
  if constexpr (P < 3) {
    constexpr int m = 1 << P;
#pragma unroll
    for (int r0 = 0; r0 < 8; ++r0) {
      if (!(r0 & m)) {
        int r1 = r0 | m;
        v2f a0 = a[r0], a1 = a[r1];
        a[r0] = c * a0 + s * vmk(a1.y, -a1.x);
        a[r1] = c * a1 + s * vmk(a0.y, -a0.x);
      }
    }
  } else {
    constexpr int xm = 1 << lanebit_of(P);
#pragma unroll
    for (int r = 0; r < 8; ++r) {
      v2f wv = lxor2<xm>(a[r]);
      a[r] = c * a[r] + s * vmk(wv.y, -wv.x);
    }
  }
}

template<int P, int Q>
__device__ __forceinline__ void crx_gate(v2f (&a)[8], float c, float s, Ctx& ctx) {
  if constexpr (Q == 6) {
    if (ctx.wbit) crx_all<P>(a, c, s, ctx);   // wave-uniform control; no syncs inside
  } else if constexpr (P == 6) {
    const float2* wp = xchg(a, ctx);
#pragma unroll
    for (int r = 0; r < 8; ++r) {
      if (act_of<Q>(r, ctx.lane)) {
        float2 w = wp[r * 64];
        a[r] = c * a[r] + s * vmk(w.y, -w.x);
      }
    }
  } else if constexpr (P < 3) {
    constexpr int m = 1 << P;
#pragma unroll
    for (int r0 = 0; r0 < 8; ++r0) {
      if (!(r0 & m)) {
        int r1 = r0 | m;
        if (act_of<Q>(r0, ctx.lane)) {
          v2f a0 = a[r0], a1 = a[r1];
          a[r0] = c * a0 + s * vmk(a1.y, -a1.x);
          a[r1] = c * a1 + s * vmk(a0.y, -a0.x);
        }
      }
    }
  } else {
    constexpr int xm = 1 << lanebit_of(P);
#pragma unroll
    for (int r = 0; r < 8; ++r) {
      v2f wv = lxor2<xm>(a[r]);
      if (act_of<Q>(r, ctx.lane)) a[r] = c * a[r] + s * vmk(wv.y, -wv.x);
    }
  }
}

// Direct LDS read of the gate's (sin,cos): constexpr offset from sc base.
template<bool ADJ, int G>
__device__ __forceinline__ void one_gate(v2f (&a)[8], const float2* sc, Ctx& ctx) {
  constexpr Gate g = GTC.g[ADJ ? (39 - G) : G];
  float2 scv = sc[g.pidx];
  float s = ADJ ? -scv.x : scv.x;
  float c = scv.y;
  if constexpr (g.ry != 0) ry_gate<g.tbit>(a, c, s, ctx);
  else crx_gate<g.tbit, g.cbit>(a, c, s, ctx);
}

template<bool ADJ, int... I>
__device__ __forceinline__ void run_layer_impl(v2f (&a)[8], const float2* sc,
                                               Ctx& ctx, std::integer_sequence<int, I...>) {
  (one_gate<ADJ, I>(a, sc, ctx), ...);
}

template<bool ADJ>
__device__ __forceinline__ void run_layer(v2f (&a)[8], const float2* sc, Ctx& ctx) {
  run_layer_impl<ADJ>(a, sc, ctx, std::make_integer_sequence<int, 40>{});
}

// ---------------- the fused kernel ----------------
__global__ __launch_bounds__(256, 1) void k_fused(const float* __restrict__ x,
                                                  const float* __restrict__ W_fp,
                                                  const float* __restrict__ b_fp,
                                                  const float* __restrict__ prep,
                                                  const float* __restrict__ sig,
                                                  const float* __restrict__ qff,
                                                  const float* __restrict__ W_out,
                                                  const float* __restrict__ b_out,
                                                  float* __restrict__ out,
                                                  float4* __restrict__ part1,
                                                  float4* __restrict__ part2,
                                                  float* __restrict__ sv) {
  int blk = blockIdx.x;
  // XCD-local remap: blk = sub*16 + b  ->  all 8 subs of b share blk%8 = b%8
  int b = blk & 15, sub = blk >> 4;
  int tid = threadIdx.x;
  int w = tid >> 6, lane = tid & 63;
  int c = w >> 1, wbit = w & 1;
  int aa = sub * 2 + c;               // this column's ancilla index

  __shared__ float2 X[2][2][2][8][64];       // [c][buf][wbit][r][lane] 16 KB
  __shared__ __align__(16) float2 R2[1024];  // 8 KB partial [wbit][r][lane]
  __shared__ __align__(16) float h[2][64];
  __shared__ float2 scs[2][80];
  __shared__ float2 qscs[40];
  __shared__ float2 ps[32];
  __shared__ float2 es[4];
  __shared__ float2 u0s[16];

  // sv zero (ordered before final atomics via barrier release chain)
  if (sub == 0 && w == 0 && lane < 30) sv[b * 30 + lane] = 0.f;

  // ---- phase 0a: h rows + small tables ----
  if (wbit == 0) {
    int f = lane, k = f >> 1;
    float div = expf(-(float)(2 * k) * (logf(10000.f) / 64.f));
    float ang = (float)aa * div;
    float pe = (f & 1) ? cosf(ang) : sinf(ang);
    h[c][f] = x[(b * 64 + f) * 16 + aa] + pe;
  }
  if (w == 1) {
    if (lane < 32) {
      float s, cc;
      sincosf(0.5f * prep[lane], &s, &cc);
      ps[lane] = make_float2(s, cc);
    } else if (lane < 36) {
      float s, cc;
      sincosf(sig[lane - 32], &s, &cc);
      es[lane - 32] = make_float2(cc, s);
    }
  } else if (w == 3 && lane < 40) {
    float s, cc;
    sincosf(0.5f * qff[lane], &s, &cc);
    qscs[lane] = make_float2(s, cc);
  }
  __syncthreads();

  // ---- phase 0b: wave 0 builds u0 = (prepare)|0>_anc ----
  if (w == 0) {
    float2 v[16];
#pragma unroll
    for (int i = 0; i < 16; ++i) v[i] = make_float2(i == 0 ? 1.f : 0.f, 0.f);
#pragma unroll 1
    for (int ly = 0; ly < 4; ++ly) {
#pragma unroll
      for (int qi = 0; qi < 4; ++qi) {
        int p = 3 - qi;
        float2 rc = ps[ly * 8 + qi * 2 + 0];      // ry
        {
          float s = rc.x, cc = rc.y;
#pragma unroll
          for (int m = 0; m < 8; ++m) {
            int a0 = insert_zero(m, p), a1 = a0 | (1 << p);
            float2 t0 = v[a0], t1 = v[a1];
            v[a0] = make_float2(cc * t0.x - s * t1.x, cc * t0.y - s * t1.y);
            v[a1] = make_float2(s * t0.x + cc * t1.x, s * t0.y + cc * t1.y);
          }
        }
        rc = ps[ly * 8 + qi * 2 + 1];             // rz
        {
          float s = rc.x, cc = rc.y;
#pragma unroll
          for (int m = 0; m < 8; ++m) {
            int a0 = insert_zero(m, p), a1 = a0 | (1 << p);
            float2 t0 = v[a0], t1 = v[a1];
            v[a0] = make_float2(cc * t0.x + s * t0.y, cc * t0.y - s * t0.x);
            v[a1] = make_float2(cc * t1.x - s * t1.y, cc * t1.y + s * t1.x);
          }
        }
      }
#pragma unroll
      for (int i = 0; i < 3; ++i) {
        int pc = 3 - i, pt = 2 - i;
#pragma unroll
        for (int m = 0; m < 4; ++m) {
          int mm = insert_zero(m, pt);
          mm = insert_zero(mm, pc);
          int a0 = mm | (1 << pc), a1 = a0 | (1 << pt);
          float2 t0 = v[a0], t1 = v[a1];
          v[a0] = t1; v[a1] = t0;
        }
      }
    }
    if (lane == 0) {
#pragma unroll
      for (int i = 0; i < 16; ++i) u0s[i] = v[i];
    }
  }

  // ---- phase 0c: ts dot products (each wave does 40 of its column's 80) ----
  if (lane < 40) {
    int j = wbit * 40 + lane;
    const float4* h4 = (const float4*)&h[c][0];
    float acc = b_fp[j];
    const float4* w4 = (const float4*)(W_fp + j * 64);
#pragma unroll
    for (int k4 = 0; k4 < 16; ++k4) {
      float4 hh = h4[k4], ww = w4[k4];
      acc += hh.x * ww.x + hh.y * ww.y + hh.z * ww.z + hh.w * ww.w;
    }
    float sg = 1.f / (1.f + expf(-acc));
    float s, cc;
    sincosf(sg * 3.14159265358979323846f, &s, &cc);   // theta/2 = sigmoid*pi
    scs[c][j] = make_float2(s, cc);
  }
  __syncthreads();                     // u0s + scs + es visible

  float2 u0aa = u0s[aa];
  float2 e0 = es[0], e1 = es[1], e2 = es[2];
  float2 m0  = cmul(u0aa, e0);
  float2 cu0 = conj2(u0aa);
  float2 ceA = conj2(e1);
  float2 wA  = make_float2(-2.f * e1.y * u0aa.y, 2.f * e1.y * u0aa.x);
  float2 ceB = conj2(e2);
  float2 wB  = make_float2(-2.f * e2.y * u0aa.y, 2.f * e2.y * u0aa.x);

  Ctx ctx;
  ctx.lane = lane; ctx.wbit = wbit; ctx.buf = 0;
  ctx.xo0 = &X[c][0][wbit][0][lane];
  ctx.xo1 = &X[c][1][wbit][0][lane];
  ctx.xp0 = &X[c][0][wbit ^ 1][0][lane];
  ctx.xp1 = &X[c][1][wbit ^ 1][0][lane];

  const float2* sc = &scs[c][0];
  v2f a[8];
#pragma unroll
  for (int r = 0; r < 8; ++r) a[r] = vmk(0.f, 0.f);
  if (wbit == 0 && lane == 0) a[0] = vmk(m0.x, m0.y);   // n = 0

  // ---- 7 layer-passes; mixes before passes 2 and 4 ----
  // ph: 0 F sc | 1 F sc+40 | 2 mix1,A sc+40 | 3 A sc | 4 mix2,F sc | 5 F sc+40 | 6 F qscs
#pragma unroll 1
  for (int ph = 0; ph < 7; ++ph) {
    if (ph == 2 || ph == 4) {
      float2 ce = (ph == 2) ? ceA : ceB;
      float2 wk = (ph == 2) ? wA : wB;
      float4* part = (ph == 2) ? part1 : part2;
      int base = wbit * 512 + lane;    // [wbit][r][lane], element stride 64

      __syncthreads();               // R2 free
      if (c == 0) {
#pragma unroll
        for (int r = 0; r < 8; ++r)
          R2[base + r * 64] = cmul(cu0, make_float2(a[r].x, a[r].y));
      }
      __syncthreads();
      if (c == 1) {
#pragma unroll
        for (int r = 0; r < 8; ++r) {
          float2 v = R2[base + r * 64];
          float2 p = cmul(cu0, make_float2(a[r].x, a[r].y));
          R2[base + r * 64] = make_float2(v.x + p.x, v.y + p.y);
        }
      }
      __syncthreads();
      // block partial -> global (linear byte copy; 512 float4, 2/thread)
      {
        float4* dst = part + (size_t)(b * 8 + sub) * 512;
        const float4* src = (const float4*)R2;
        dst[tid] = src[tid];
        dst[tid + 256] = src[tid + 256];
      }
      group_barrier32(b, lane);      // release covers stores; acquire for reads

      // s = own block partial (LDS) + 7 remote block partials (XCD-local L2);
      // FULLY unrolled -> all 56 loads issued before the wait.
      float2 s2[8];
#pragma unroll
      for (int r = 0; r < 8; ++r) s2[r] = R2[base + r * 64];
#pragma unroll
      for (int o = 1; o < 8; ++o) {
        int so = (sub + o) & 7;
        const float2* pp = (const float2*)(part + (size_t)(b * 8 + so) * 512);
#pragma unroll
        for (int r = 0; r < 8; ++r) {
          float2 v = pp[base + r * 64];
          s2[r].x += v.x; s2[r].y += v.y;
        }
      }
      // col <- ce*col + wk*s
#pragma unroll
      for (int r = 0; r < 8; ++r) {
        v2f a0 = a[r];
        a[r] = vmk(ce.x * a0.x - ce.y * a0.y + wk.x * s2[r].x - wk.y * s2[r].y,
                   ce.x * a0.y + ce.y * a0.x + wk.x * s2[r].y + wk.y * s2[r].x);
      }
    }
    const float2* scp;
    if (ph == 6) scp = &qscs[0];
    else scp = sc + ((ph == 1 || ph == 2 || ph == 5) ? 40 : 0);
    if (ph == 2 || ph == 3) run_layer<true>(a, scp, ctx);
    else                    run_layer<false>(a, scp, ctx);
  }

  // ---- expvals ----
  {
    float obs[30];
#pragma unroll
    for (int p = 0; p <= 9; ++p) {
      int i = 9 - p;
      float cr = 0.f, ci = 0.f, zz = 0.f;
      if (p < 3) {
        int m = 1 << p;
#pragma unroll
        for (int r0 = 0; r0 < 8; ++r0) {
          if (!(r0 & m)) {
            v2f A0 = a[r0], A1 = a[r0 | m];
            cr += A0.x * A1.x + A0.y * A1.y;
            ci += A0.x * A1.y - A0.y * A1.x;
            zz += (A0.x * A0.x + A0.y * A0.y) - (A1.x * A1.x + A1.y * A1.y);
          }
        }
      } else if (p == 6) {
        // cross-wave observable: exchange, low half computes cr/ci
        float2* wo = ctx.buf ? ctx.xo1 : ctx.xo0;
#pragma unroll
        for (int r = 0; r < 8; ++r) wo[r * 64] = make_float2(a[r].x, a[r].y);
        __syncthreads();
        const float2* wp = ctx.buf ? ctx.xp1 : ctx.xp0;
        ctx.buf ^= 1;
#pragma unroll
        for (int r = 0; r < 8; ++r) {
          float n2 = a[r].x * a[r].x + a[r].y * a[r].y;
          if (wbit == 0) {
            float2 ww = wp[r * 64];
            cr += a[r].x * ww.x + a[r].y * ww.y;
            ci += a[r].x * ww.y - a[r].y * ww.x;
            zz += n2;
          } else {
            zz -= n2;
          }
        }
      } else {
        int lb = (p == 3) ? 0 : (p == 4) ? 1 : (p == 5) ? 2 : (p == 7) ? 3 : (p == 8) ? 4 : 5;
        int xm = 1 << lb;
        bool up = (lane >> lb) & 1;
#pragma unroll
        for (int r = 0; r < 8; ++r) {
          float wx = __shfl_xor(a[r].x, xm, 64);
          float wy = __shfl_xor(a[r].y, xm, 64);
          float n2 = a[r].x * a[r].x + a[r].y * a[r].y;
          if (!up) {
            cr += a[r].x * wx + a[r].y * wy;
            ci += a[r].x * wy - a[r].y * wx;
            zz += n2;
          } else {
            zz -= n2;
          }
        }
      }
      obs[i] = 2.f * cr;
      obs[10 + i] = 2.f * ci;
      obs[20 + i] = zz;
    }
#pragma unroll
    for (int j = 0; j < 30; ++j) obs[j] = wave_sum(obs[j]);

    float* Rf = (float*)R2;
    __syncthreads();                 // R2 free (mix-2 gather long done)
    if (lane == 0) {
#pragma unroll
      for (int j = 0; j < 30; ++j) Rf[w * 30 + j] = obs[j];
    }
    __syncthreads();
    if (w == 0) {
      if (lane < 30) {
        float v = Rf[0 * 30 + lane] + Rf[1 * 30 + lane] +
                  Rf[2 * 30 + lane] + Rf[3 * 30 + lane];
        atomicAdd(&sv[b * 30 + lane], v);
      }
      // last-arriving block of group b computes the output row
      int lastflag = 0;
      if (lane == 0) {
        unsigned old = __hip_atomic_fetch_add(&g_gb[b].done, 1u, __ATOMIC_ACQ_REL,
                                              __HIP_MEMORY_SCOPE_AGENT);
        lastflag = ((old & 7u) == 7u) ? 1 : 0;
      }
      lastflag = __shfl(lastflag, 0, 64);
      if (lastflag) {
        (void)__hip_atomic_load(&g_gb[b].done, __ATOMIC_ACQUIRE, __HIP_MEMORY_SCOPE_AGENT);
        if (lane < 8) {
          float acc = b_out[lane];
#pragma unroll
          for (int j = 0; j < 30; ++j) acc += W_out[lane * 30 + j] * sv[b * 30 + j];
          out[b * 8 + lane] = acc;
        }
      }
    }
  }
}

extern "C" void kernel_launch(void* const* d_in, const int* in_sizes, int n_in,
                              void* d_out, int out_size, void* d_ws, size_t ws_size,
                              hipStream_t stream) {
  const float* x     = (const float*)d_in[0];
  const float* W_fp  = (const float*)d_in[1];
  const float* b_fp  = (const float*)d_in[2];
  const float* prep  = (const float*)d_in[3];
  const float* sig   = (const float*)d_in[4];
  const float* qff   = (const float*)d_in[5];
  const float* W_out = (const float*)d_in[6];
  const float* b_out = (const float*)d_in[7];
  float* out = (float*)d_out;
  (void)in_sizes; (void)n_in; (void)out_size;

  // ws: part1 (1 MB) | part2 (1 MB) | sv (1920 B). Needs ~2.1 MB.
  char* ws = (char*)d_ws;
  const size_t SZ_PART = (size_t)128 * 512 * 16;   // 128 block-partials * 8 KB
  float4* part1 = (float4*)ws;
  float4* part2 = (float4*)(ws + SZ_PART);
  float*  sv    = (float*)(ws + 2 * SZ_PART);
  (void)ws_size;

  k_fused<<<dim3(128), dim3(256), 0, stream>>>(x, W_fp, b_fp, prep, sig, qff,
                                               W_out, b_out, out, part1, part2, sv);
}